// Round 18
// baseline (276.349 us; speedup 1.0000x reference)
//
#include <hip/hip_runtime.h>
#include <hip/hip_bf16.h>
#include <cstddef>

#define NA 200000   // atoms
#define EA 800000   // atom-graph edges
#define NF 20000    // fragments
#define EF 60000    // fragment-graph edges
// D = 128, hidden = 256
#define TOTW (EA + NA + EF)   // build-pass work items (1060000)
#define CAPE 32               // max in-degree (atom edges; Poisson mean 4)
#define CAPA 64               // max atoms/frag (Poisson mean 10)
#define CAPF 32               // max frag-edge in-degree (Poisson mean 3)
#define GRIDY (NA / 64)       // fused-kernel grid (3125 blocks)
#define CSTR 40               // chunk LDS row stride in ushorts (80B)

typedef unsigned short ushort_t;
typedef __attribute__((ext_vector_type(8))) short bf16x8;
typedef __attribute__((ext_vector_type(4))) float f32x4;

__device__ __forceinline__ unsigned short f2bf(float f) {
  unsigned u = __builtin_bit_cast(unsigned, f);
  u += 0x7FFFu + ((u >> 16) & 1u);  // round-to-nearest-even
  return (unsigned short)(u >> 16);
}
// fma 2 bf16 packed in a uint (lo, hi) scaled by s
__device__ __forceinline__ void acc2s(float& a, float& b, unsigned v, float s) {
  a = fmaf(__builtin_bit_cast(float, v << 16), s, a);
  b = fmaf(__builtin_bit_cast(float, v & 0xFFFF0000u), s, b);
}

// ======== Wt[c][k] = bf16(W[k][c]) — tiny precompute ========================
__global__ __launch_bounds__(256) void k_wt(const float* __restrict__ W,
                                            ushort_t* __restrict__ Wt) {
  int idx = blockIdx.x * 256 + threadIdx.x;  // 16384
  if (idx < 128 * 128) {
    int c = idx >> 7, k = idx & 127;
    Wt[idx] = f2bf(W[k * 128 + c]);
  }
}

// ======= fused: CSR build (atomic wall) + MFMA GEMM (hides under it) ========
// The scattered-atomic wall (~1.86M ops, ~19-26 G/s: R6-R14) is LATENCY-
// limited: R14 drained it in 103us at 70% occupancy; R15/R17's 52KB LDS
// capped occupancy at 30% (125us). Fix: K-chunked staging (4 chunks of K=32)
// -> 15KB LDS -> 7 blocks/CU (28 waves). Chunk layout: row stride 40 ushorts,
// fragment perm pos(k) = g*8 + j + 4h (k = g*4 + j + 16h) so each lane's
// MFMA fragment is ONE contiguous 16B ds_read_b128; per-16-lane phases have
// bank starts 20*row + 4g mod 32 -> each 4-bank window hit exactly 2x.
__global__ __launch_bounds__(256) void k_fused(
    const int* __restrict__ ei, const int* __restrict__ a2f,
    const int* __restrict__ fi, int* __restrict__ cnt_src,
    int* __restrict__ cnt_e, int* __restrict__ cnt_a, int* __restrict__ cnt_f,
    int* __restrict__ lst_e, int* __restrict__ lst_a, int* __restrict__ lst_f,
    const float* __restrict__ xa, const ushort_t* __restrict__ Wt,
    const float* __restrict__ b, ushort_t* __restrict__ y) {
  __shared__ ushort_t Asl[64 * CSTR];    // 5.0 KB
  __shared__ ushort_t Bsl[128 * CSTR];   // 10.0 KB
  const int tid = threadIdx.x;
  const int brow = blockIdx.x * 64;

  // ---- phase 1: build items (grid-stride; 1-2 per thread) ----
  for (int idx = blockIdx.x * 256 + tid; idx < TOTW; idx += GRIDY * 256) {
    if (idx < EA) {
      int s = ei[idx], t = ei[EA + idx];
      atomicAdd(&cnt_src[s], 1);                 // out-degree (for dinv)
      int p = atomicAdd(&cnt_e[t], 1);
      if (p < CAPE) lst_e[t * CAPE + p] = s;
    } else if (idx < EA + NA) {
      int i = idx - EA;
      int f = a2f[i];
      int p = atomicAdd(&cnt_a[f], 1);
      if (p < CAPA) lst_a[f * CAPA + p] = i;
    } else {
      int e = idx - EA - NA;
      int p = atomicAdd(&cnt_f[fi[EF + e]], 1);
      if (p < CAPF) lst_f[fi[EF + e] * CAPF + p] = fi[e];
    }
  }

  // ---- phase 2: GEMM y = bf16(x@W + b), K-chunked (4 x K=32) ----
  const int w = tid >> 6;
  const int l = tid & 63;
  const int lr = l & 15;
  const int g = l >> 4;
  const int r0 = w * 16;
  const int arow = r0 + lr;
  f32x4 acc[8] = {};
#pragma unroll
  for (int s = 0; s < 4; ++s) {
    if (s > 0) __syncthreads();  // all reads of chunk s-1 done
    {  // stage A chunk: 64 rows x 32 k. thread -> (row, kq_local), 2 units
      const float4* gA = reinterpret_cast<const float4*>(xa + (size_t)brow * 128);
#pragma unroll
      for (int i = 0; i < 2; ++i) {
        int f = tid + i * 256;          // 0..511
        int row = f >> 3;               // 0..63
        int kq = f & 7;                 // float4 unit within chunk
        float4 v = gA[row * 32 + s * 8 + kq];
        ushort4 u;
        u.x = f2bf(v.x); u.y = f2bf(v.y); u.z = f2bf(v.z); u.w = f2bf(v.w);
        int off = ((kq & 3) << 3) | ((kq >> 2) << 2);  // g'*8 + 4h
        *reinterpret_cast<ushort4*>(&Asl[row * CSTR + off]) = u;
      }
      // stage B chunk: 128 cols x 32 k. thread -> (c, k8_local), 2 units
      const uint4* gW = reinterpret_cast<const uint4*>(Wt);
#pragma unroll
      for (int i = 0; i < 2; ++i) {
        int f = tid + i * 256;          // 0..511
        int c = f >> 2;                 // 0..127
        int k8 = f & 3;                 // 8-ushort unit within chunk
        uint4 v = gW[c * 16 + s * 4 + k8];
        int base0 = ((k8 & 1) << 4) | ((k8 >> 1) << 2);  // g'*8 + 4h
        uint2 lo, hi;
        lo.x = v.x; lo.y = v.y;  // j=0..3 of g' even part
        hi.x = v.z; hi.y = v.w;  // next g-half (+8)
        *reinterpret_cast<uint2*>(&Bsl[c * CSTR + base0]) = lo;
        *reinterpret_cast<uint2*>(&Bsl[c * CSTR + base0 + 8]) = hi;
      }
    }
    __syncthreads();
    bf16x8 a = *reinterpret_cast<const bf16x8*>(&Asl[arow * CSTR + g * 8]);
#pragma unroll
    for (int t = 0; t < 8; ++t) {
      bf16x8 bf = *reinterpret_cast<const bf16x8*>(&Bsl[(t * 16 + lr) * CSTR + g * 8]);
      acc[t] = __builtin_amdgcn_mfma_f32_16x16x32_bf16(a, bf, acc[t], 0, 0, 0);
    }
  }
#pragma unroll
  for (int t = 0; t < 8; ++t) {
    const int col = t * 16 + lr;
    const float bb = b[col];
#pragma unroll
    for (int r = 0; r < 4; ++r) {
      const int row = brow + r0 + g * 4 + r;
      y[(size_t)row * 128 + col] = f2bf(acc[t][r] + bb);
    }
  }
}

// ==== x_new[t] = dinv[t] * (y[t]*dinv[t] + sum_{s->t} y[s]*dinv[s]) =========
__global__ __launch_bounds__(256) void k_gather_x(
    const int* __restrict__ cnt_e, const int* __restrict__ lst_e,
    const ushort_t* __restrict__ y, const int* __restrict__ cnt_src,
    float* __restrict__ xnew) {
  const int row = blockIdx.x * 16 + (threadIdx.x >> 4);
  const int lane = threadIdx.x & 15;
  const int c0 = lane * 8;  // bf16 units
  const float dt = rsqrtf(1.0f + (float)cnt_src[row]);
  float a0 = 0, a1 = 0, a2 = 0, a3 = 0, a4 = 0, a5 = 0, a6 = 0, a7 = 0;
  {
    uint4 v = *reinterpret_cast<const uint4*>(y + (size_t)row * 128 + c0);
    acc2s(a0, a1, v.x, dt); acc2s(a2, a3, v.y, dt);
    acc2s(a4, a5, v.z, dt); acc2s(a6, a7, v.w, dt);
  }
  const int base = row * CAPE;
  int deg = cnt_e[row];
  deg = (deg < CAPE) ? deg : CAPE;
  int j = 0;
  for (; j + 4 <= deg; j += 4) {
    const int s0 = lst_e[base + j + 0];
    const int s1 = lst_e[base + j + 1];
    const int s2 = lst_e[base + j + 2];
    const int s3 = lst_e[base + j + 3];
    const float d0 = rsqrtf(1.0f + (float)cnt_src[s0]);
    const float d1 = rsqrtf(1.0f + (float)cnt_src[s1]);
    const float d2 = rsqrtf(1.0f + (float)cnt_src[s2]);
    const float d3 = rsqrtf(1.0f + (float)cnt_src[s3]);
    const uint4 w0 = *reinterpret_cast<const uint4*>(y + (size_t)s0 * 128 + c0);
    const uint4 w1 = *reinterpret_cast<const uint4*>(y + (size_t)s1 * 128 + c0);
    const uint4 w2 = *reinterpret_cast<const uint4*>(y + (size_t)s2 * 128 + c0);
    const uint4 w3 = *reinterpret_cast<const uint4*>(y + (size_t)s3 * 128 + c0);
    acc2s(a0, a1, w0.x, d0); acc2s(a2, a3, w0.y, d0); acc2s(a4, a5, w0.z, d0); acc2s(a6, a7, w0.w, d0);
    acc2s(a0, a1, w1.x, d1); acc2s(a2, a3, w1.y, d1); acc2s(a4, a5, w1.z, d1); acc2s(a6, a7, w1.w, d1);
    acc2s(a0, a1, w2.x, d2); acc2s(a2, a3, w2.y, d2); acc2s(a4, a5, w2.z, d2); acc2s(a6, a7, w2.w, d2);
    acc2s(a0, a1, w3.x, d3); acc2s(a2, a3, w3.y, d3); acc2s(a4, a5, w3.z, d3); acc2s(a6, a7, w3.w, d3);
  }
  for (; j < deg; ++j) {
    const int s = lst_e[base + j];
    const float dn = rsqrtf(1.0f + (float)cnt_src[s]);
    const uint4 w = *reinterpret_cast<const uint4*>(y + (size_t)s * 128 + c0);
    acc2s(a0, a1, w.x, dn); acc2s(a2, a3, w.y, dn);
    acc2s(a4, a5, w.z, dn); acc2s(a6, a7, w.w, dn);
  }
  f32x4 q0 = {a0 * dt, a1 * dt, a2 * dt, a3 * dt};
  f32x4 q1 = {a4 * dt, a5 * dt, a6 * dt, a7 * dt};
  float* o = xnew + (size_t)row * 128 + c0;
  __builtin_nontemporal_store(q0, reinterpret_cast<f32x4*>(o));
  __builtin_nontemporal_store(q1, reinterpret_cast<f32x4*>(o + 4));
}

// ======== ff[f] = sum_{atoms i in f} xnew[i] ================================
__global__ __launch_bounds__(256) void k_gather_ff(
    const int* __restrict__ cnt_a, const int* __restrict__ lst_a,
    const float* __restrict__ xnew, float* __restrict__ ff) {
  const int f = blockIdx.x * 8 + (threadIdx.x >> 5);
  const int c = (threadIdx.x & 31) << 2;
  float4 acc = {0.f, 0.f, 0.f, 0.f};
  const int base = f * CAPA;
  int deg = cnt_a[f];
  deg = (deg < CAPA) ? deg : CAPA;
  int j = 0;
  for (; j + 4 <= deg; j += 4) {
    const int s0 = lst_a[base + j + 0];
    const int s1 = lst_a[base + j + 1];
    const int s2 = lst_a[base + j + 2];
    const int s3 = lst_a[base + j + 3];
    const float4 v0 = *reinterpret_cast<const float4*>(xnew + (size_t)s0 * 128 + c);
    const float4 v1 = *reinterpret_cast<const float4*>(xnew + (size_t)s1 * 128 + c);
    const float4 v2 = *reinterpret_cast<const float4*>(xnew + (size_t)s2 * 128 + c);
    const float4 v3 = *reinterpret_cast<const float4*>(xnew + (size_t)s3 * 128 + c);
    acc.x += v0.x + v1.x + v2.x + v3.x;
    acc.y += v0.y + v1.y + v2.y + v3.y;
    acc.z += v0.z + v1.z + v2.z + v3.z;
    acc.w += v0.w + v1.w + v2.w + v3.w;
  }
  for (; j < deg; ++j) {
    const int s = lst_a[base + j];
    const float4 v = *reinterpret_cast<const float4*>(xnew + (size_t)s * 128 + c);
    acc.x += v.x; acc.y += v.y; acc.z += v.z; acc.w += v.w;
  }
  *reinterpret_cast<float4*>(ff + (size_t)f * 128 + c) = acc;
}

// ======== fused: fsum gather (frag edges) + 2-layer MLP =====================
__global__ __launch_bounds__(256) void k_mlp(
    const int* __restrict__ cnt_f, const int* __restrict__ lst_f,
    const float* __restrict__ ff,
    const float* __restrict__ W1, const float* __restrict__ b1,
    const float* __restrict__ W2, const float* __restrict__ b2,
    float* __restrict__ out) {
  __shared__ float As[32][128];
  __shared__ float hs[32][256];
  const int row0 = blockIdx.x * 32;
  {  // gather: 8 groups x 32 lanes; each group handles 4 rows
    const int g = threadIdx.x >> 5;
    const int c = (threadIdx.x & 31) << 2;
#pragma unroll
    for (int rr = 0; rr < 4; ++rr) {
      const int f = row0 + g * 4 + rr;
      const int base = f * CAPF;
      int deg = cnt_f[f];
      deg = (deg < CAPF) ? deg : CAPF;
      float4 acc = {0.f, 0.f, 0.f, 0.f};
      for (int j = 0; j < deg; ++j) {
        const int s = lst_f[base + j];
        const float4 v = *reinterpret_cast<const float4*>(ff + (size_t)s * 128 + c);
        acc.x += v.x; acc.y += v.y; acc.z += v.z; acc.w += v.w;
      }
      *reinterpret_cast<float4*>(&As[g * 4 + rr][c]) = acc;
    }
  }
  __syncthreads();
  {  // GEMM1
    const int tc = threadIdx.x & 63;
    const int tr = threadIdx.x >> 6;
    const int c0 = tc * 4;
    float acc[8][4] = {};
    for (int k0 = 0; k0 < 128; k0 += 4) {
      float4 w0 = *reinterpret_cast<const float4*>(&W1[(k0 + 0) * 256 + c0]);
      float4 w1 = *reinterpret_cast<const float4*>(&W1[(k0 + 1) * 256 + c0]);
      float4 w2 = *reinterpret_cast<const float4*>(&W1[(k0 + 2) * 256 + c0]);
      float4 w3 = *reinterpret_cast<const float4*>(&W1[(k0 + 3) * 256 + c0]);
#pragma unroll
      for (int r = 0; r < 8; ++r) {
        float4 a = *reinterpret_cast<const float4*>(&As[tr * 8 + r][k0]);
        acc[r][0] += a.x * w0.x + a.y * w1.x + a.z * w2.x + a.w * w3.x;
        acc[r][1] += a.x * w0.y + a.y * w1.y + a.z * w2.y + a.w * w3.y;
        acc[r][2] += a.x * w0.z + a.y * w1.z + a.z * w2.z + a.w * w3.z;
        acc[r][3] += a.x * w0.w + a.y * w1.w + a.z * w2.w + a.w * w3.w;
      }
    }
    const float4 bc = *reinterpret_cast<const float4*>(&b1[c0]);
#pragma unroll
    for (int r = 0; r < 8; ++r) {
      float4 h;
      h.x = fmaxf(acc[r][0] + bc.x, 0.f);
      h.y = fmaxf(acc[r][1] + bc.y, 0.f);
      h.z = fmaxf(acc[r][2] + bc.z, 0.f);
      h.w = fmaxf(acc[r][3] + bc.w, 0.f);
      *reinterpret_cast<float4*>(&hs[tr * 8 + r][c0]) = h;
    }
  }
  __syncthreads();
  {  // GEMM2
    const int tc = threadIdx.x & 31;
    const int tr = threadIdx.x >> 5;
    const int c0 = tc * 4;
    float acc[4][4] = {};
    for (int k0 = 0; k0 < 256; k0 += 4) {
      float4 w0 = *reinterpret_cast<const float4*>(&W2[(k0 + 0) * 128 + c0]);
      float4 w1 = *reinterpret_cast<const float4*>(&W2[(k0 + 1) * 128 + c0]);
      float4 w2 = *reinterpret_cast<const float4*>(&W2[(k0 + 2) * 128 + c0]);
      float4 w3 = *reinterpret_cast<const float4*>(&W2[(k0 + 3) * 128 + c0]);
#pragma unroll
      for (int r = 0; r < 4; ++r) {
        float4 a = *reinterpret_cast<const float4*>(&hs[tr * 4 + r][k0]);
        acc[r][0] += a.x * w0.x + a.y * w1.x + a.z * w2.x + a.w * w3.x;
        acc[r][1] += a.x * w0.y + a.y * w1.y + a.z * w2.y + a.w * w3.y;
        acc[r][2] += a.x * w0.z + a.y * w1.z + a.z * w2.z + a.w * w3.z;
        acc[r][3] += a.x * w0.w + a.y * w1.w + a.z * w2.w + a.w * w3.w;
      }
    }
    const float4 bc = *reinterpret_cast<const float4*>(&b2[c0]);
#pragma unroll
    for (int r = 0; r < 4; ++r) {
      float4 o;
      o.x = acc[r][0] + bc.x;
      o.y = acc[r][1] + bc.y;
      o.z = acc[r][2] + bc.z;
      o.w = acc[r][3] + bc.w;
      *reinterpret_cast<float4*>(&out[(size_t)(row0 + tr * 4 + r) * 128 + c0]) = o;
    }
  }
}

extern "C" void kernel_launch(void* const* d_in, const int* in_sizes, int n_in,
                              void* d_out, int out_size, void* d_ws, size_t ws_size,
                              hipStream_t stream) {
  // Bond-graph GAT inputs are dead code w.r.t. the returned outputs.
  const float* x_atoms    = (const float*)d_in[0];
  const int*   edge_index = (const int*)d_in[1];
  const int*   frag_index = (const int*)d_in[3];
  const int*   a2f        = (const int*)d_in[5];
  const float* W_atom     = (const float*)d_in[9];
  const float* b_atom     = (const float*)d_in[10];
  const float* W_f1       = (const float*)d_in[16];
  const float* b_f1       = (const float*)d_in[17];
  const float* W_f2       = (const float*)d_in[18];
  const float* b_f2       = (const float*)d_in[19];

  char* ws = (char*)d_ws;
  size_t off = 0;
  auto alloc = [&](size_t bytes) {
    void* p = ws + off;
    off += (bytes + 255) & ~(size_t)255;
    return p;
  };
  // --- zeroed-each-call pool (counters; 1.8 MB) ---
  int* cnt_src = (int*)alloc((size_t)NA * 4);
  int* cnt_e   = (int*)alloc((size_t)NA * 4);
  int* cnt_a   = (int*)alloc((size_t)NF * 4);
  int* cnt_f   = (int*)alloc((size_t)NF * 4);
  const size_t zero_bytes = off;
  // --- rebuilt-each-call ---
  int* lst_e   = (int*)alloc((size_t)NA * CAPE * 4);   // 25.6 MB
  int* lst_a   = (int*)alloc((size_t)NF * CAPA * 4);   // 5.1 MB
  int* lst_f   = (int*)alloc((size_t)NF * CAPF * 4);   // 2.6 MB
  ushort_t* Wt = (ushort_t*)alloc((size_t)128 * 128 * 2);
  ushort_t* y  = (ushort_t*)alloc((size_t)NA * 128 * 2);  // bf16, 51.2 MB
  float* ff    = (float*)alloc((size_t)NF * 128 * 4);     // 10.2 MB

  float* xnew = (float*)d_out;                     // [NA,128]
  float* fout = (float*)d_out + (size_t)NA * 128;  // [NF,128]

  (void)hipMemsetAsync(ws, 0, zero_bytes, stream);

  k_wt<<<64, 256, 0, stream>>>(W_atom, Wt);
  k_fused<<<GRIDY, 256, 0, stream>>>(edge_index, a2f, frag_index,
                                     cnt_src, cnt_e, cnt_a, cnt_f,
                                     lst_e, lst_a, lst_f,
                                     x_atoms, Wt, b_atom, y);
  k_gather_x<<<NA / 16, 256, 0, stream>>>(cnt_e, lst_e, y, cnt_src, xnew);
  k_gather_ff<<<NF / 8, 256, 0, stream>>>(cnt_a, lst_a, xnew, ff);
  k_mlp     <<<NF / 32, 256, 0, stream>>>(cnt_f, lst_f, ff, W_f1, b_f1,
                                          W_f2, b_f2, fout);
}

// Round 19
// 264.360 us; speedup vs baseline: 1.0454x; 1.0454x over previous
//
#include <hip/hip_runtime.h>
#include <hip/hip_bf16.h>
#include <cstddef>

#define NA 200000   // atoms
#define EA 800000   // atom-graph edges
#define NF 20000    // fragments
#define EF 60000    // fragment-graph edges
// D = 128, hidden = 256
#define TOTW (EA + NA + EF)   // build-pass work items (1060000)
#define CAPE 32               // max in-degree (atom edges; Poisson mean 4)
#define CAPA 64               // max atoms/frag (Poisson mean 10)
#define CAPF 32               // max frag-edge in-degree (Poisson mean 3)
#define GRIDY (NA / 64)       // fused-kernel grid (3125 blocks)
#define CSTR 40               // chunk LDS row stride in ushorts (80B)
#define NCNT (2 * NA + 2 * NF) // total counter words (zeroed each call)

typedef unsigned short ushort_t;
typedef __attribute__((ext_vector_type(8))) short bf16x8;
typedef __attribute__((ext_vector_type(4))) float f32x4;

__device__ __forceinline__ unsigned short f2bf(float f) {
  unsigned u = __builtin_bit_cast(unsigned, f);
  u += 0x7FFFu + ((u >> 16) & 1u);  // round-to-nearest-even
  return (unsigned short)(u >> 16);
}
// fma 2 bf16 packed in a uint (lo, hi) scaled by s
__device__ __forceinline__ void acc2s(float& a, float& b, unsigned v, float s) {
  a = fmaf(__builtin_bit_cast(float, v << 16), s, a);
  b = fmaf(__builtin_bit_cast(float, v & 0xFFFF0000u), s, b);
}
__device__ __forceinline__ void acc2(float& a, float& b, unsigned v) {
  a += __builtin_bit_cast(float, v << 16);
  b += __builtin_bit_cast(float, v & 0xFFFF0000u);
}

// ======== init: zero counters + Wt[c][k] = bf16(W[k][c]) (one launch) =======
__global__ __launch_bounds__(256) void k_init(const float* __restrict__ W,
                                              ushort_t* __restrict__ Wt,
                                              int* __restrict__ cnts) {
  int idx = blockIdx.x * 256 + threadIdx.x;
  if (idx < NCNT) cnts[idx] = 0;
  if (idx < 128 * 128) {
    int c = idx >> 7, k = idx & 127;
    Wt[idx] = f2bf(W[k * 128 + c]);
  }
}

// ======= fused: CSR build (atomic wall) + MFMA GEMM (hides under it) ========
// The scattered-atomic wall is OP-COUNT-proportional (~19 G/s) and
// insensitive to occupancy/LDS/type/privatization (R6-R18). GEMM overlaps.
__global__ __launch_bounds__(256) void k_fused(
    const int* __restrict__ ei, const int* __restrict__ a2f,
    const int* __restrict__ fi, int* __restrict__ cnt_src,
    int* __restrict__ cnt_e, int* __restrict__ cnt_a, int* __restrict__ cnt_f,
    int* __restrict__ lst_e, int* __restrict__ lst_a, int* __restrict__ lst_f,
    const float* __restrict__ xa, const ushort_t* __restrict__ Wt,
    const float* __restrict__ b, ushort_t* __restrict__ y) {
  __shared__ ushort_t Asl[64 * CSTR];    // 5.0 KB
  __shared__ ushort_t Bsl[128 * CSTR];   // 10.0 KB
  const int tid = threadIdx.x;
  const int brow = blockIdx.x * 64;

  // ---- phase 1: build items (grid-stride; 1-2 per thread) ----
  for (int idx = blockIdx.x * 256 + tid; idx < TOTW; idx += GRIDY * 256) {
    if (idx < EA) {
      int s = ei[idx], t = ei[EA + idx];
      atomicAdd(&cnt_src[s], 1);                 // out-degree (for dinv)
      int p = atomicAdd(&cnt_e[t], 1);
      if (p < CAPE) lst_e[t * CAPE + p] = s;
    } else if (idx < EA + NA) {
      int i = idx - EA;
      int f = a2f[i];
      int p = atomicAdd(&cnt_a[f], 1);
      if (p < CAPA) lst_a[f * CAPA + p] = i;
    } else {
      int e = idx - EA - NA;
      int p = atomicAdd(&cnt_f[fi[EF + e]], 1);
      if (p < CAPF) lst_f[fi[EF + e] * CAPF + p] = fi[e];
    }
  }

  // ---- phase 2: GEMM y = bf16(x@W + b), K-chunked (4 x K=32) ----
  const int w = tid >> 6;
  const int l = tid & 63;
  const int lr = l & 15;
  const int g = l >> 4;
  const int r0 = w * 16;
  const int arow = r0 + lr;
  f32x4 acc[8] = {};
#pragma unroll
  for (int s = 0; s < 4; ++s) {
    if (s > 0) __syncthreads();  // all reads of chunk s-1 done
    {  // stage A chunk: 64 rows x 32 k
      const float4* gA = reinterpret_cast<const float4*>(xa + (size_t)brow * 128);
#pragma unroll
      for (int i = 0; i < 2; ++i) {
        int f = tid + i * 256;
        int row = f >> 3;
        int kq = f & 7;
        float4 v = gA[row * 32 + s * 8 + kq];
        ushort4 u;
        u.x = f2bf(v.x); u.y = f2bf(v.y); u.z = f2bf(v.z); u.w = f2bf(v.w);
        int off = ((kq & 3) << 3) | ((kq >> 2) << 2);  // g'*8 + 4h
        *reinterpret_cast<ushort4*>(&Asl[row * CSTR + off]) = u;
      }
      // stage B chunk: 128 cols x 32 k
      const uint4* gW = reinterpret_cast<const uint4*>(Wt);
#pragma unroll
      for (int i = 0; i < 2; ++i) {
        int f = tid + i * 256;
        int c = f >> 2;
        int k8 = f & 3;
        uint4 v = gW[c * 16 + s * 4 + k8];
        int base0 = ((k8 & 1) << 4) | ((k8 >> 1) << 2);
        uint2 lo, hi;
        lo.x = v.x; lo.y = v.y;
        hi.x = v.z; hi.y = v.w;
        *reinterpret_cast<uint2*>(&Bsl[c * CSTR + base0]) = lo;
        *reinterpret_cast<uint2*>(&Bsl[c * CSTR + base0 + 8]) = hi;
      }
    }
    __syncthreads();
    bf16x8 a = *reinterpret_cast<const bf16x8*>(&Asl[arow * CSTR + g * 8]);
#pragma unroll
    for (int t = 0; t < 8; ++t) {
      bf16x8 bf = *reinterpret_cast<const bf16x8*>(&Bsl[(t * 16 + lr) * CSTR + g * 8]);
      acc[t] = __builtin_amdgcn_mfma_f32_16x16x32_bf16(a, bf, acc[t], 0, 0, 0);
    }
  }
#pragma unroll
  for (int t = 0; t < 8; ++t) {
    const int col = t * 16 + lr;
    const float bb = b[col];
#pragma unroll
    for (int r = 0; r < 4; ++r) {
      const int row = brow + r0 + g * 4 + r;
      y[(size_t)row * 128 + col] = f2bf(acc[t][r] + bb);
    }
  }
}

// ==== x_new[t] = dinv[t] * (y[t]*dinv[t] + sum_{s->t} y[s]*dinv[s]) =========
// Emits fp32 xnew (output) AND a bf16 sidecar for the downstream random
// reads of k_gather_ff (halves its L3 random-read bytes).
__global__ __launch_bounds__(256) void k_gather_x(
    const int* __restrict__ cnt_e, const int* __restrict__ lst_e,
    const ushort_t* __restrict__ y, const int* __restrict__ cnt_src,
    float* __restrict__ xnew, ushort_t* __restrict__ x16) {
  const int row = blockIdx.x * 16 + (threadIdx.x >> 4);
  const int lane = threadIdx.x & 15;
  const int c0 = lane * 8;  // bf16 units
  const float dt = rsqrtf(1.0f + (float)cnt_src[row]);
  float a0 = 0, a1 = 0, a2 = 0, a3 = 0, a4 = 0, a5 = 0, a6 = 0, a7 = 0;
  {
    uint4 v = *reinterpret_cast<const uint4*>(y + (size_t)row * 128 + c0);
    acc2s(a0, a1, v.x, dt); acc2s(a2, a3, v.y, dt);
    acc2s(a4, a5, v.z, dt); acc2s(a6, a7, v.w, dt);
  }
  const int base = row * CAPE;
  int deg = cnt_e[row];
  deg = (deg < CAPE) ? deg : CAPE;
  int j = 0;
  for (; j + 4 <= deg; j += 4) {
    const int s0 = lst_e[base + j + 0];
    const int s1 = lst_e[base + j + 1];
    const int s2 = lst_e[base + j + 2];
    const int s3 = lst_e[base + j + 3];
    const float d0 = rsqrtf(1.0f + (float)cnt_src[s0]);
    const float d1 = rsqrtf(1.0f + (float)cnt_src[s1]);
    const float d2 = rsqrtf(1.0f + (float)cnt_src[s2]);
    const float d3 = rsqrtf(1.0f + (float)cnt_src[s3]);
    const uint4 w0 = *reinterpret_cast<const uint4*>(y + (size_t)s0 * 128 + c0);
    const uint4 w1 = *reinterpret_cast<const uint4*>(y + (size_t)s1 * 128 + c0);
    const uint4 w2 = *reinterpret_cast<const uint4*>(y + (size_t)s2 * 128 + c0);
    const uint4 w3 = *reinterpret_cast<const uint4*>(y + (size_t)s3 * 128 + c0);
    acc2s(a0, a1, w0.x, d0); acc2s(a2, a3, w0.y, d0); acc2s(a4, a5, w0.z, d0); acc2s(a6, a7, w0.w, d0);
    acc2s(a0, a1, w1.x, d1); acc2s(a2, a3, w1.y, d1); acc2s(a4, a5, w1.z, d1); acc2s(a6, a7, w1.w, d1);
    acc2s(a0, a1, w2.x, d2); acc2s(a2, a3, w2.y, d2); acc2s(a4, a5, w2.z, d2); acc2s(a6, a7, w2.w, d2);
    acc2s(a0, a1, w3.x, d3); acc2s(a2, a3, w3.y, d3); acc2s(a4, a5, w3.z, d3); acc2s(a6, a7, w3.w, d3);
  }
  for (; j < deg; ++j) {
    const int s = lst_e[base + j];
    const float dn = rsqrtf(1.0f + (float)cnt_src[s]);
    const uint4 w = *reinterpret_cast<const uint4*>(y + (size_t)s * 128 + c0);
    acc2s(a0, a1, w.x, dn); acc2s(a2, a3, w.y, dn);
    acc2s(a4, a5, w.z, dn); acc2s(a6, a7, w.w, dn);
  }
  a0 *= dt; a1 *= dt; a2 *= dt; a3 *= dt;
  a4 *= dt; a5 *= dt; a6 *= dt; a7 *= dt;
  f32x4 q0 = {a0, a1, a2, a3};
  f32x4 q1 = {a4, a5, a6, a7};
  float* o = xnew + (size_t)row * 128 + c0;
  __builtin_nontemporal_store(q0, reinterpret_cast<f32x4*>(o));
  __builtin_nontemporal_store(q1, reinterpret_cast<f32x4*>(o + 4));
  ushort4 h0, h1;
  h0.x = f2bf(a0); h0.y = f2bf(a1); h0.z = f2bf(a2); h0.w = f2bf(a3);
  h1.x = f2bf(a4); h1.y = f2bf(a5); h1.z = f2bf(a6); h1.w = f2bf(a7);
  uint4 hp;
  hp.x = (unsigned)h0.x | ((unsigned)h0.y << 16);
  hp.y = (unsigned)h0.z | ((unsigned)h0.w << 16);
  hp.z = (unsigned)h1.x | ((unsigned)h1.y << 16);
  hp.w = (unsigned)h1.z | ((unsigned)h1.w << 16);
  *reinterpret_cast<uint4*>(x16 + (size_t)row * 128 + c0) = hp;
}

// ======== ff[f] = sum_{atoms i in f} xnew[i]  (bf16 sidecar reads) ==========
__global__ __launch_bounds__(256) void k_gather_ff(
    const int* __restrict__ cnt_a, const int* __restrict__ lst_a,
    const ushort_t* __restrict__ x16, float* __restrict__ ff) {
  const int f = blockIdx.x * 16 + (threadIdx.x >> 4);
  const int lane = threadIdx.x & 15;
  const int c0 = lane * 8;  // bf16 units
  float a0 = 0, a1 = 0, a2 = 0, a3 = 0, a4 = 0, a5 = 0, a6 = 0, a7 = 0;
  const int base = f * CAPA;
  int deg = cnt_a[f];
  deg = (deg < CAPA) ? deg : CAPA;
  int j = 0;
  for (; j + 4 <= deg; j += 4) {
    const int s0 = lst_a[base + j + 0];
    const int s1 = lst_a[base + j + 1];
    const int s2 = lst_a[base + j + 2];
    const int s3 = lst_a[base + j + 3];
    const uint4 w0 = *reinterpret_cast<const uint4*>(x16 + (size_t)s0 * 128 + c0);
    const uint4 w1 = *reinterpret_cast<const uint4*>(x16 + (size_t)s1 * 128 + c0);
    const uint4 w2 = *reinterpret_cast<const uint4*>(x16 + (size_t)s2 * 128 + c0);
    const uint4 w3 = *reinterpret_cast<const uint4*>(x16 + (size_t)s3 * 128 + c0);
    acc2(a0, a1, w0.x); acc2(a2, a3, w0.y); acc2(a4, a5, w0.z); acc2(a6, a7, w0.w);
    acc2(a0, a1, w1.x); acc2(a2, a3, w1.y); acc2(a4, a5, w1.z); acc2(a6, a7, w1.w);
    acc2(a0, a1, w2.x); acc2(a2, a3, w2.y); acc2(a4, a5, w2.z); acc2(a6, a7, w2.w);
    acc2(a0, a1, w3.x); acc2(a2, a3, w3.y); acc2(a4, a5, w3.z); acc2(a6, a7, w3.w);
  }
  for (; j < deg; ++j) {
    const int s = lst_a[base + j];
    const uint4 w = *reinterpret_cast<const uint4*>(x16 + (size_t)s * 128 + c0);
    acc2(a0, a1, w.x); acc2(a2, a3, w.y); acc2(a4, a5, w.z); acc2(a6, a7, w.w);
  }
  f32x4 q0 = {a0, a1, a2, a3};
  f32x4 q1 = {a4, a5, a6, a7};
  float* o = ff + (size_t)f * 128 + c0;
  *reinterpret_cast<f32x4*>(o) = q0;
  *reinterpret_cast<f32x4*>(o + 4) = q1;
}

// ======== fused: fsum gather (frag edges) + 2-layer MLP =====================
__global__ __launch_bounds__(256) void k_mlp(
    const int* __restrict__ cnt_f, const int* __restrict__ lst_f,
    const float* __restrict__ ff,
    const float* __restrict__ W1, const float* __restrict__ b1,
    const float* __restrict__ W2, const float* __restrict__ b2,
    float* __restrict__ out) {
  __shared__ float As[32][128];
  __shared__ float hs[32][256];
  const int row0 = blockIdx.x * 32;
  {  // gather: 8 groups x 32 lanes; each group handles 4 rows
    const int g = threadIdx.x >> 5;
    const int c = (threadIdx.x & 31) << 2;
#pragma unroll
    for (int rr = 0; rr < 4; ++rr) {
      const int f = row0 + g * 4 + rr;
      const int base = f * CAPF;
      int deg = cnt_f[f];
      deg = (deg < CAPF) ? deg : CAPF;
      float4 acc = {0.f, 0.f, 0.f, 0.f};
      for (int j = 0; j < deg; ++j) {
        const int s = lst_f[base + j];
        const float4 v = *reinterpret_cast<const float4*>(ff + (size_t)s * 128 + c);
        acc.x += v.x; acc.y += v.y; acc.z += v.z; acc.w += v.w;
      }
      *reinterpret_cast<float4*>(&As[g * 4 + rr][c]) = acc;
    }
  }
  __syncthreads();
  {  // GEMM1
    const int tc = threadIdx.x & 63;
    const int tr = threadIdx.x >> 6;
    const int c0 = tc * 4;
    float acc[8][4] = {};
    for (int k0 = 0; k0 < 128; k0 += 4) {
      float4 w0 = *reinterpret_cast<const float4*>(&W1[(k0 + 0) * 256 + c0]);
      float4 w1 = *reinterpret_cast<const float4*>(&W1[(k0 + 1) * 256 + c0]);
      float4 w2 = *reinterpret_cast<const float4*>(&W1[(k0 + 2) * 256 + c0]);
      float4 w3 = *reinterpret_cast<const float4*>(&W1[(k0 + 3) * 256 + c0]);
#pragma unroll
      for (int r = 0; r < 8; ++r) {
        float4 a = *reinterpret_cast<const float4*>(&As[tr * 8 + r][k0]);
        acc[r][0] += a.x * w0.x + a.y * w1.x + a.z * w2.x + a.w * w3.x;
        acc[r][1] += a.x * w0.y + a.y * w1.y + a.z * w2.y + a.w * w3.y;
        acc[r][2] += a.x * w0.z + a.y * w1.z + a.z * w2.z + a.w * w3.z;
        acc[r][3] += a.x * w0.w + a.y * w1.w + a.z * w2.w + a.w * w3.w;
      }
    }
    const float4 bc = *reinterpret_cast<const float4*>(&b1[c0]);
#pragma unroll
    for (int r = 0; r < 8; ++r) {
      float4 h;
      h.x = fmaxf(acc[r][0] + bc.x, 0.f);
      h.y = fmaxf(acc[r][1] + bc.y, 0.f);
      h.z = fmaxf(acc[r][2] + bc.z, 0.f);
      h.w = fmaxf(acc[r][3] + bc.w, 0.f);
      *reinterpret_cast<float4*>(&hs[tr * 8 + r][c0]) = h;
    }
  }
  __syncthreads();
  {  // GEMM2
    const int tc = threadIdx.x & 31;
    const int tr = threadIdx.x >> 5;
    const int c0 = tc * 4;
    float acc[4][4] = {};
    for (int k0 = 0; k0 < 256; k0 += 4) {
      float4 w0 = *reinterpret_cast<const float4*>(&W2[(k0 + 0) * 128 + c0]);
      float4 w1 = *reinterpret_cast<const float4*>(&W2[(k0 + 1) * 128 + c0]);
      float4 w2 = *reinterpret_cast<const float4*>(&W2[(k0 + 2) * 128 + c0]);
      float4 w3 = *reinterpret_cast<const float4*>(&W2[(k0 + 3) * 128 + c0]);
#pragma unroll
      for (int r = 0; r < 4; ++r) {
        float4 a = *reinterpret_cast<const float4*>(&hs[tr * 4 + r][k0]);
        acc[r][0] += a.x * w0.x + a.y * w1.x + a.z * w2.x + a.w * w3.x;
        acc[r][1] += a.x * w0.y + a.y * w1.y + a.z * w2.y + a.w * w3.y;
        acc[r][2] += a.x * w0.z + a.y * w1.z + a.z * w2.z + a.w * w3.z;
        acc[r][3] += a.x * w0.w + a.y * w1.w + a.z * w2.w + a.w * w3.w;
      }
    }
    const float4 bc = *reinterpret_cast<const float4*>(&b2[c0]);
#pragma unroll
    for (int r = 0; r < 4; ++r) {
      float4 o;
      o.x = acc[r][0] + bc.x;
      o.y = acc[r][1] + bc.y;
      o.z = acc[r][2] + bc.z;
      o.w = acc[r][3] + bc.w;
      *reinterpret_cast<float4*>(&out[(size_t)(row0 + tr * 4 + r) * 128 + c0]) = o;
    }
  }
}

extern "C" void kernel_launch(void* const* d_in, const int* in_sizes, int n_in,
                              void* d_out, int out_size, void* d_ws, size_t ws_size,
                              hipStream_t stream) {
  // Bond-graph GAT inputs are dead code w.r.t. the returned outputs.
  const float* x_atoms    = (const float*)d_in[0];
  const int*   edge_index = (const int*)d_in[1];
  const int*   frag_index = (const int*)d_in[3];
  const int*   a2f        = (const int*)d_in[5];
  const float* W_atom     = (const float*)d_in[9];
  const float* b_atom     = (const float*)d_in[10];
  const float* W_f1       = (const float*)d_in[16];
  const float* b_f1       = (const float*)d_in[17];
  const float* W_f2       = (const float*)d_in[18];
  const float* b_f2       = (const float*)d_in[19];

  char* ws = (char*)d_ws;
  size_t off = 0;
  auto alloc = [&](size_t bytes) {
    void* p = ws + off;
    off += (bytes + 255) & ~(size_t)255;
    return p;
  };
  // --- counters: ONE contiguous block, zeroed by k_init (1.76 MB) ---
  int* cnts    = (int*)alloc((size_t)NCNT * 4);
  int* cnt_src = cnts;
  int* cnt_e   = cnts + NA;
  int* cnt_a   = cnts + 2 * NA;
  int* cnt_f   = cnts + 2 * NA + NF;
  // --- rebuilt-each-call ---
  int* lst_e   = (int*)alloc((size_t)NA * CAPE * 4);   // 25.6 MB
  int* lst_a   = (int*)alloc((size_t)NF * CAPA * 4);   // 5.1 MB
  int* lst_f   = (int*)alloc((size_t)NF * CAPF * 4);   // 2.6 MB
  ushort_t* Wt = (ushort_t*)alloc((size_t)128 * 128 * 2);
  ushort_t* y  = (ushort_t*)alloc((size_t)NA * 128 * 2);   // 51.2 MB
  ushort_t* x16 = (ushort_t*)alloc((size_t)NA * 128 * 2);  // 51.2 MB sidecar
  float* ff    = (float*)alloc((size_t)NF * 128 * 4);      // 10.2 MB

  float* xnew = (float*)d_out;                     // [NA,128]
  float* fout = (float*)d_out + (size_t)NA * 128;  // [NF,128]

  k_init<<<(NCNT + 255) / 256, 256, 0, stream>>>(W_atom, Wt, cnts);
  k_fused<<<GRIDY, 256, 0, stream>>>(edge_index, a2f, frag_index,
                                     cnt_src, cnt_e, cnt_a, cnt_f,
                                     lst_e, lst_a, lst_f,
                                     x_atoms, Wt, b_atom, y);
  k_gather_x<<<NA / 16, 256, 0, stream>>>(cnt_e, lst_e, y, cnt_src, xnew, x16);
  k_gather_ff<<<NF / 16, 256, 0, stream>>>(cnt_a, lst_a, x16, ff);
  k_mlp<<<NF / 32, 256, 0, stream>>>(cnt_f, lst_f, ff, W_f1, b_f1,
                                     W_f2, b_f2, fout);
}

// Round 21
// 253.601 us; speedup vs baseline: 1.0897x; 1.0424x over previous
//
#include <hip/hip_runtime.h>
#include <hip/hip_bf16.h>
#include <cstddef>

#define NA 200000   // atoms
#define EA 800000   // atom-graph edges
#define NF 20000    // fragments
#define EF 60000    // fragment-graph edges
// D = 128, hidden = 256
#define CAPE 32               // max in-degree (atom edges; Poisson mean 4)
#define CAPA 64               // max atoms/frag (Poisson mean 10)
#define CAPF 32               // max frag-edge in-degree (Poisson mean 3)
#define GRIDY (NA / 64)       // fused-kernel grid (3125 blocks)
#define CSTR 40               // chunk LDS row stride in ushorts (80B)
#define NCNT (2 * NA + 2 * NF) // total counter words (zeroed each call)
#define GRIDX (NA / 16)       // gather_x grid (12500 blocks)

typedef unsigned short ushort_t;
typedef __attribute__((ext_vector_type(8))) short bf16x8;
typedef __attribute__((ext_vector_type(4))) float f32x4;

__device__ __forceinline__ unsigned short f2bf(float f) {
  unsigned u = __builtin_bit_cast(unsigned, f);
  u += 0x7FFFu + ((u >> 16) & 1u);  // round-to-nearest-even
  return (unsigned short)(u >> 16);
}
// fma 2 bf16 packed in a uint (lo, hi) scaled by s
__device__ __forceinline__ void acc2s(float& a, float& b, unsigned v, float s) {
  a = fmaf(__builtin_bit_cast(float, v << 16), s, a);
  b = fmaf(__builtin_bit_cast(float, v & 0xFFFF0000u), s, b);
}
__device__ __forceinline__ void acc2(float& a, float& b, unsigned v) {
  a += __builtin_bit_cast(float, v << 16);
  b += __builtin_bit_cast(float, v & 0xFFFF0000u);
}

// ======== init: zero counters + Wt[c][k] = bf16(W[k][c]) (one launch) =======
__global__ __launch_bounds__(256) void k_init(const float* __restrict__ W,
                                              ushort_t* __restrict__ Wt,
                                              int* __restrict__ cnts) {
  int idx = blockIdx.x * 256 + threadIdx.x;
  if (idx < NCNT) cnts[idx] = 0;
  if (idx < 128 * 128) {
    int c = idx >> 7, k = idx & 127;
    Wt[idx] = f2bf(W[k * 128 + c]);
  }
}

// ======= fused: EDGE CSR build (atomic wall) + MFMA GEMM (hides under it) ===
// The scattered-atomic wall is OP-COUNT-proportional (~19 G/s, one 32B
// coherence-point sector per atomic) and insensitive to occupancy/LDS/type/
// privatization (R6-R19). Frag-build atomics (260K) moved to k_gather_x's
// prologue -> this kernel's wall is 1.6M atomics.
__global__ __launch_bounds__(256) void k_fused(
    const int* __restrict__ ei, int* __restrict__ cnt_src,
    int* __restrict__ cnt_e, int* __restrict__ lst_e,
    const float* __restrict__ xa, const ushort_t* __restrict__ Wt,
    const float* __restrict__ b, ushort_t* __restrict__ y) {
  __shared__ ushort_t Asl[64 * CSTR];    // 5.0 KB
  __shared__ ushort_t Bsl[128 * CSTR];   // 10.0 KB
  const int tid = threadIdx.x;
  const int brow = blockIdx.x * 64;

  // ---- phase 1: edge-build items (grid-stride; 1 per thread) ----
  for (int idx = blockIdx.x * 256 + tid; idx < EA; idx += GRIDY * 256) {
    int s = ei[idx], t = ei[EA + idx];
    atomicAdd(&cnt_src[s], 1);                 // out-degree (for dinv)
    int p = atomicAdd(&cnt_e[t], 1);
    if (p < CAPE) lst_e[t * CAPE + p] = s;
  }

  // ---- phase 2: GEMM y = bf16(x@W + b), K-chunked (4 x K=32) ----
  const int w = tid >> 6;
  const int l = tid & 63;
  const int lr = l & 15;
  const int g = l >> 4;
  const int r0 = w * 16;
  const int arow = r0 + lr;
  f32x4 acc[8] = {};
#pragma unroll
  for (int s = 0; s < 4; ++s) {
    if (s > 0) __syncthreads();  // all reads of chunk s-1 done
    {  // stage A chunk: 64 rows x 32 k
      const float4* gA = reinterpret_cast<const float4*>(xa + (size_t)brow * 128);
#pragma unroll
      for (int i = 0; i < 2; ++i) {
        int f = tid + i * 256;
        int row = f >> 3;
        int kq = f & 7;
        float4 v = gA[row * 32 + s * 8 + kq];
        ushort4 u;
        u.x = f2bf(v.x); u.y = f2bf(v.y); u.z = f2bf(v.z); u.w = f2bf(v.w);
        int off = ((kq & 3) << 3) | ((kq >> 2) << 2);  // g'*8 + 4h
        *reinterpret_cast<ushort4*>(&Asl[row * CSTR + off]) = u;
      }
      // stage B chunk: 128 cols x 32 k
      const uint4* gW = reinterpret_cast<const uint4*>(Wt);
#pragma unroll
      for (int i = 0; i < 2; ++i) {
        int f = tid + i * 256;
        int c = f >> 2;
        int k8 = f & 3;
        uint4 v = gW[c * 16 + s * 4 + k8];
        int base0 = ((k8 & 1) << 4) | ((k8 >> 1) << 2);
        uint2 lo, hi;
        lo.x = v.x; lo.y = v.y;
        hi.x = v.z; hi.y = v.w;
        *reinterpret_cast<uint2*>(&Bsl[c * CSTR + base0]) = lo;
        *reinterpret_cast<uint2*>(&Bsl[c * CSTR + base0 + 8]) = hi;
      }
    }
    __syncthreads();
    bf16x8 a = *reinterpret_cast<const bf16x8*>(&Asl[arow * CSTR + g * 8]);
#pragma unroll
    for (int t = 0; t < 8; ++t) {
      bf16x8 bf = *reinterpret_cast<const bf16x8*>(&Bsl[(t * 16 + lr) * CSTR + g * 8]);
      acc[t] = __builtin_amdgcn_mfma_f32_16x16x32_bf16(a, bf, acc[t], 0, 0, 0);
    }
  }
#pragma unroll
  for (int t = 0; t < 8; ++t) {
    const int col = t * 16 + lr;
    const float bb = b[col];
#pragma unroll
    for (int r = 0; r < 4; ++r) {
      const int row = brow + r0 + g * 4 + r;
      y[(size_t)row * 128 + col] = f2bf(acc[t][r] + bb);
    }
  }
}

// ==== frag-build prologue + x_new gather ====================================
// Prologue: 260K frag-build atomics (1 per ~12 threads) hide under this
// kernel's L3-latency-bound gather. Their consumers (gather_ff/mlp) launch
// later, so completion-by-kernel-end suffices.
// Gather: x_new[t] = dinv[t]*(y[t]*dinv[t] + sum y[s]*dinv[s]); emits fp32
// output + bf16 sidecar for gather_ff.
__global__ __launch_bounds__(256) void k_gather_x(
    const int* __restrict__ a2f, const int* __restrict__ fi,
    int* __restrict__ cnt_a, int* __restrict__ cnt_f,
    int* __restrict__ lst_a, int* __restrict__ lst_f,
    const int* __restrict__ cnt_e, const int* __restrict__ lst_e,
    const ushort_t* __restrict__ y, const int* __restrict__ cnt_src,
    float* __restrict__ xnew, ushort_t* __restrict__ x16) {
  {  // frag-build: NA + EF = 260K items over 3.2M threads (single pass)
    int idx = blockIdx.x * 256 + threadIdx.x;
    if (idx < NA) {
      int f = a2f[idx];
      int p = atomicAdd(&cnt_a[f], 1);
      if (p < CAPA) lst_a[f * CAPA + p] = idx;
    } else if (idx < NA + EF) {
      int e = idx - NA;
      int t = fi[EF + e];
      int p = atomicAdd(&cnt_f[t], 1);
      if (p < CAPF) lst_f[t * CAPF + p] = fi[e];
    }
  }
  const int row = blockIdx.x * 16 + (threadIdx.x >> 4);
  const int lane = threadIdx.x & 15;
  const int c0 = lane * 8;  // bf16 units
  const float dt = rsqrtf(1.0f + (float)cnt_src[row]);
  float a0 = 0, a1 = 0, a2 = 0, a3 = 0, a4 = 0, a5 = 0, a6 = 0, a7 = 0;
  {
    uint4 v = *reinterpret_cast<const uint4*>(y + (size_t)row * 128 + c0);
    acc2s(a0, a1, v.x, dt); acc2s(a2, a3, v.y, dt);
    acc2s(a4, a5, v.z, dt); acc2s(a6, a7, v.w, dt);
  }
  const int base = row * CAPE;
  int deg = cnt_e[row];
  deg = (deg < CAPE) ? deg : CAPE;
  int j = 0;
  for (; j + 4 <= deg; j += 4) {
    const int s0 = lst_e[base + j + 0];
    const int s1 = lst_e[base + j + 1];
    const int s2 = lst_e[base + j + 2];
    const int s3 = lst_e[base + j + 3];
    const float d0 = rsqrtf(1.0f + (float)cnt_src[s0]);
    const float d1 = rsqrtf(1.0f + (float)cnt_src[s1]);
    const float d2 = rsqrtf(1.0f + (float)cnt_src[s2]);
    const float d3 = rsqrtf(1.0f + (float)cnt_src[s3]);
    const uint4 w0 = *reinterpret_cast<const uint4*>(y + (size_t)s0 * 128 + c0);
    const uint4 w1 = *reinterpret_cast<const uint4*>(y + (size_t)s1 * 128 + c0);
    const uint4 w2 = *reinterpret_cast<const uint4*>(y + (size_t)s2 * 128 + c0);
    const uint4 w3 = *reinterpret_cast<const uint4*>(y + (size_t)s3 * 128 + c0);
    acc2s(a0, a1, w0.x, d0); acc2s(a2, a3, w0.y, d0); acc2s(a4, a5, w0.z, d0); acc2s(a6, a7, w0.w, d0);
    acc2s(a0, a1, w1.x, d1); acc2s(a2, a3, w1.y, d1); acc2s(a4, a5, w1.z, d1); acc2s(a6, a7, w1.w, d1);
    acc2s(a0, a1, w2.x, d2); acc2s(a2, a3, w2.y, d2); acc2s(a4, a5, w2.z, d2); acc2s(a6, a7, w2.w, d2);
    acc2s(a0, a1, w3.x, d3); acc2s(a2, a3, w3.y, d3); acc2s(a4, a5, w3.z, d3); acc2s(a6, a7, w3.w, d3);
  }
  for (; j < deg; ++j) {
    const int s = lst_e[base + j];
    const float dn = rsqrtf(1.0f + (float)cnt_src[s]);
    const uint4 w = *reinterpret_cast<const uint4*>(y + (size_t)s * 128 + c0);
    acc2s(a0, a1, w.x, dn); acc2s(a2, a3, w.y, dn);
    acc2s(a4, a5, w.z, dn); acc2s(a6, a7, w.w, dn);
  }
  a0 *= dt; a1 *= dt; a2 *= dt; a3 *= dt;
  a4 *= dt; a5 *= dt; a6 *= dt; a7 *= dt;
  f32x4 q0 = {a0, a1, a2, a3};
  f32x4 q1 = {a4, a5, a6, a7};
  float* o = xnew + (size_t)row * 128 + c0;
  __builtin_nontemporal_store(q0, reinterpret_cast<f32x4*>(o));
  __builtin_nontemporal_store(q1, reinterpret_cast<f32x4*>(o + 4));
  uint4 hp;
  hp.x = (unsigned)f2bf(a0) | ((unsigned)f2bf(a1) << 16);
  hp.y = (unsigned)f2bf(a2) | ((unsigned)f2bf(a3) << 16);
  hp.z = (unsigned)f2bf(a4) | ((unsigned)f2bf(a5) << 16);
  hp.w = (unsigned)f2bf(a6) | ((unsigned)f2bf(a7) << 16);
  *reinterpret_cast<uint4*>(x16 + (size_t)row * 128 + c0) = hp;
}

// ======== ff[f] = sum_{atoms i in f} xnew[i]  (bf16 sidecar reads) ==========
__global__ __launch_bounds__(256) void k_gather_ff(
    const int* __restrict__ cnt_a, const int* __restrict__ lst_a,
    const ushort_t* __restrict__ x16, float* __restrict__ ff) {
  const int f = blockIdx.x * 16 + (threadIdx.x >> 4);
  const int lane = threadIdx.x & 15;
  const int c0 = lane * 8;  // bf16 units
  float a0 = 0, a1 = 0, a2 = 0, a3 = 0, a4 = 0, a5 = 0, a6 = 0, a7 = 0;
  const int base = f * CAPA;
  int deg = cnt_a[f];
  deg = (deg < CAPA) ? deg : CAPA;
  int j = 0;
  for (; j + 4 <= deg; j += 4) {
    const int s0 = lst_a[base + j + 0];
    const int s1 = lst_a[base + j + 1];
    const int s2 = lst_a[base + j + 2];
    const int s3 = lst_a[base + j + 3];
    const uint4 w0 = *reinterpret_cast<const uint4*>(x16 + (size_t)s0 * 128 + c0);
    const uint4 w1 = *reinterpret_cast<const uint4*>(x16 + (size_t)s1 * 128 + c0);
    const uint4 w2 = *reinterpret_cast<const uint4*>(x16 + (size_t)s2 * 128 + c0);
    const uint4 w3 = *reinterpret_cast<const uint4*>(x16 + (size_t)s3 * 128 + c0);
    acc2(a0, a1, w0.x); acc2(a2, a3, w0.y); acc2(a4, a5, w0.z); acc2(a6, a7, w0.w);
    acc2(a0, a1, w1.x); acc2(a2, a3, w1.y); acc2(a4, a5, w1.z); acc2(a6, a7, w1.w);
    acc2(a0, a1, w2.x); acc2(a2, a3, w2.y); acc2(a4, a5, w2.z); acc2(a6, a7, w2.w);
    acc2(a0, a1, w3.x); acc2(a2, a3, w3.y); acc2(a4, a5, w3.z); acc2(a6, a7, w3.w);
  }
  for (; j < deg; ++j) {
    const int s = lst_a[base + j];
    const uint4 w = *reinterpret_cast<const uint4*>(x16 + (size_t)s * 128 + c0);
    acc2(a0, a1, w.x); acc2(a2, a3, w.y); acc2(a4, a5, w.z); acc2(a6, a7, w.w);
  }
  f32x4 q0 = {a0, a1, a2, a3};
  f32x4 q1 = {a4, a5, a6, a7};
  float* o = ff + (size_t)f * 128 + c0;
  *reinterpret_cast<f32x4*>(o) = q0;
  *reinterpret_cast<f32x4*>(o + 4) = q1;
}

// ======== fused: fsum gather (frag edges) + 2-layer MLP =====================
__global__ __launch_bounds__(256) void k_mlp(
    const int* __restrict__ cnt_f, const int* __restrict__ lst_f,
    const float* __restrict__ ff,
    const float* __restrict__ W1, const float* __restrict__ b1,
    const float* __restrict__ W2, const float* __restrict__ b2,
    float* __restrict__ out) {
  __shared__ float As[32][128];
  __shared__ float hs[32][256];
  const int row0 = blockIdx.x * 32;
  {  // gather: 8 groups x 32 lanes; each group handles 4 rows
    const int g = threadIdx.x >> 5;
    const int c = (threadIdx.x & 31) << 2;
#pragma unroll
    for (int rr = 0; rr < 4; ++rr) {
      const int f = row0 + g * 4 + rr;
      const int base = f * CAPF;
      int deg = cnt_f[f];
      deg = (deg < CAPF) ? deg : CAPF;
      float4 acc = {0.f, 0.f, 0.f, 0.f};
      for (int j = 0; j < deg; ++j) {
        const int s = lst_f[base + j];
        const float4 v = *reinterpret_cast<const float4*>(ff + (size_t)s * 128 + c);
        acc.x += v.x; acc.y += v.y; acc.z += v.z; acc.w += v.w;
      }
      *reinterpret_cast<float4*>(&As[g * 4 + rr][c]) = acc;
    }
  }
  __syncthreads();
  {  // GEMM1
    const int tc = threadIdx.x & 63;
    const int tr = threadIdx.x >> 6;
    const int c0 = tc * 4;
    float acc[8][4] = {};
    for (int k0 = 0; k0 < 128; k0 += 4) {
      float4 w0 = *reinterpret_cast<const float4*>(&W1[(k0 + 0) * 256 + c0]);
      float4 w1 = *reinterpret_cast<const float4*>(&W1[(k0 + 1) * 256 + c0]);
      float4 w2 = *reinterpret_cast<const float4*>(&W1[(k0 + 2) * 256 + c0]);
      float4 w3 = *reinterpret_cast<const float4*>(&W1[(k0 + 3) * 256 + c0]);
#pragma unroll
      for (int r = 0; r < 8; ++r) {
        float4 a = *reinterpret_cast<const float4*>(&As[tr * 8 + r][k0]);
        acc[r][0] += a.x * w0.x + a.y * w1.x + a.z * w2.x + a.w * w3.x;
        acc[r][1] += a.x * w0.y + a.y * w1.y + a.z * w2.y + a.w * w3.y;
        acc[r][2] += a.x * w0.z + a.y * w1.z + a.z * w2.z + a.w * w3.z;
        acc[r][3] += a.x * w0.w + a.y * w1.w + a.z * w2.w + a.w * w3.w;
      }
    }
    const float4 bc = *reinterpret_cast<const float4*>(&b1[c0]);
#pragma unroll
    for (int r = 0; r < 8; ++r) {
      float4 h;
      h.x = fmaxf(acc[r][0] + bc.x, 0.f);
      h.y = fmaxf(acc[r][1] + bc.y, 0.f);
      h.z = fmaxf(acc[r][2] + bc.z, 0.f);
      h.w = fmaxf(acc[r][3] + bc.w, 0.f);
      *reinterpret_cast<float4*>(&hs[tr * 8 + r][c0]) = h;
    }
  }
  __syncthreads();
  {  // GEMM2
    const int tc = threadIdx.x & 31;
    const int tr = threadIdx.x >> 5;
    const int c0 = tc * 4;
    float acc[4][4] = {};
    for (int k0 = 0; k0 < 256; k0 += 4) {
      float4 w0 = *reinterpret_cast<const float4*>(&W2[(k0 + 0) * 128 + c0]);
      float4 w1 = *reinterpret_cast<const float4*>(&W2[(k0 + 1) * 128 + c0]);
      float4 w2 = *reinterpret_cast<const float4*>(&W2[(k0 + 2) * 128 + c0]);
      float4 w3 = *reinterpret_cast<const float4*>(&W2[(k0 + 3) * 128 + c0]);
#pragma unroll
      for (int r = 0; r < 4; ++r) {
        float4 a = *reinterpret_cast<const float4*>(&hs[tr * 4 + r][k0]);
        acc[r][0] += a.x * w0.x + a.y * w1.x + a.z * w2.x + a.w * w3.x;
        acc[r][1] += a.x * w0.y + a.y * w1.y + a.z * w2.y + a.w * w3.y;
        acc[r][2] += a.x * w0.z + a.y * w1.z + a.z * w2.z + a.w * w3.z;
        acc[r][3] += a.x * w0.w + a.y * w1.w + a.z * w2.w + a.w * w3.w;
      }
    }
    const float4 bc = *reinterpret_cast<const float4*>(&b2[c0]);
#pragma unroll
    for (int r = 0; r < 4; ++r) {
      float4 o;
      o.x = acc[r][0] + bc.x;
      o.y = acc[r][1] + bc.y;
      o.z = acc[r][2] + bc.z;
      o.w = acc[r][3] + bc.w;
      *reinterpret_cast<float4*>(&out[(size_t)(row0 + tr * 4 + r) * 128 + c0]) = o;
    }
  }
}

extern "C" void kernel_launch(void* const* d_in, const int* in_sizes, int n_in,
                              void* d_out, int out_size, void* d_ws, size_t ws_size,
                              hipStream_t stream) {
  // Bond-graph GAT inputs are dead code w.r.t. the returned outputs.
  const float* x_atoms    = (const float*)d_in[0];
  const int*   edge_index = (const int*)d_in[1];
  const int*   frag_index = (const int*)d_in[3];
  const int*   a2f        = (const int*)d_in[5];
  const float* W_atom     = (const float*)d_in[9];
  const float* b_atom     = (const float*)d_in[10];
  const float* W_f1       = (const float*)d_in[16];
  const float* b_f1       = (const float*)d_in[17];
  const float* W_f2       = (const float*)d_in[18];
  const float* b_f2       = (const float*)d_in[19];

  char* ws = (char*)d_ws;
  size_t off = 0;
  auto alloc = [&](size_t bytes) {
    void* p = ws + off;
    off += (bytes + 255) & ~(size_t)255;
    return p;
  };
  // --- counters: ONE contiguous block, zeroed by k_init (1.76 MB) ---
  int* cnts    = (int*)alloc((size_t)NCNT * 4);
  int* cnt_src = cnts;
  int* cnt_e   = cnts + NA;
  int* cnt_a   = cnts + 2 * NA;
  int* cnt_f   = cnts + 2 * NA + NF;
  // --- rebuilt-each-call ---
  int* lst_e   = (int*)alloc((size_t)NA * CAPE * 4);   // 25.6 MB
  int* lst_a   = (int*)alloc((size_t)NF * CAPA * 4);   // 5.1 MB
  int* lst_f   = (int*)alloc((size_t)NF * CAPF * 4);   // 2.6 MB
  ushort_t* Wt = (ushort_t*)alloc((size_t)128 * 128 * 2);
  ushort_t* y  = (ushort_t*)alloc((size_t)NA * 128 * 2);   // 51.2 MB
  ushort_t* x16 = (ushort_t*)alloc((size_t)NA * 128 * 2);  // 51.2 MB sidecar
  float* ff    = (float*)alloc((size_t)NF * 128 * 4);      // 10.2 MB

  float* xnew = (float*)d_out;                     // [NA,128]
  float* fout = (float*)d_out + (size_t)NA * 128;  // [NF,128]

  k_init<<<(NCNT + 255) / 256, 256, 0, stream>>>(W_atom, Wt, cnts);
  k_fused<<<GRIDY, 256, 0, stream>>>(edge_index, cnt_src, cnt_e, lst_e,
                                     x_atoms, Wt, b_atom, y);
  k_gather_x<<<GRIDX, 256, 0, stream>>>(a2f, frag_index, cnt_a, cnt_f,
                                        lst_a, lst_f, cnt_e, lst_e, y,
                                        cnt_src, xnew, x16);
  k_gather_ff<<<NF / 16, 256, 0, stream>>>(cnt_a, lst_a, x16, ff);
  k_mlp<<<NF / 32, 256, 0, stream>>>(cnt_f, lst_f, ff, W_f1, b_f1,
                                     W_f2, b_f2, fout);
}

// Round 22
// 248.288 us; speedup vs baseline: 1.1130x; 1.0214x over previous
//
#include <hip/hip_runtime.h>
#include <hip/hip_bf16.h>
#include <cstddef>

#define NA 200000   // atoms
#define EA 800000   // atom-graph edges
#define NF 20000    // fragments
#define EF 60000    // fragment-graph edges
// D = 128, hidden = 256
#define CAPE 32               // max in-degree (atom edges; Poisson mean 4)
#define CAPA 64               // max atoms/frag (Poisson mean 10)
#define CAPF 32               // max frag-edge in-degree (Poisson mean 3)
#define GRIDY (NA / 64)       // fused-kernel grid (3125 blocks; x256 thr == EA)
#define CSTR 40               // chunk LDS row stride in ushorts (80B)
#define NCNT (2 * NA + 2 * NF) // total counter words (zeroed each call)
#define GRIDX (NA / 16)       // gather_x grid (12500 blocks)

typedef unsigned short ushort_t;
typedef __attribute__((ext_vector_type(8))) short bf16x8;
typedef __attribute__((ext_vector_type(4))) float f32x4;

__device__ __forceinline__ unsigned short f2bf(float f) {
  unsigned u = __builtin_bit_cast(unsigned, f);
  u += 0x7FFFu + ((u >> 16) & 1u);  // round-to-nearest-even
  return (unsigned short)(u >> 16);
}
// fma 2 bf16 packed in a uint (lo, hi) scaled by s
__device__ __forceinline__ void acc2s(float& a, float& b, unsigned v, float s) {
  a = fmaf(__builtin_bit_cast(float, v << 16), s, a);
  b = fmaf(__builtin_bit_cast(float, v & 0xFFFF0000u), s, b);
}
__device__ __forceinline__ void acc2(float& a, float& b, unsigned v) {
  a += __builtin_bit_cast(float, v << 16);
  b += __builtin_bit_cast(float, v & 0xFFFF0000u);
}

// ======== init: zero counters + Wt[c][k] = bf16(W[k][c]) (one launch) =======
__global__ __launch_bounds__(256) void k_init(const float* __restrict__ W,
                                              ushort_t* __restrict__ Wt,
                                              int* __restrict__ cnts) {
  int idx = blockIdx.x * 256 + threadIdx.x;
  if (idx < NCNT) cnts[idx] = 0;
  if (idx < 128 * 128) {
    int c = idx >> 7, k = idx & 127;
    Wt[idx] = f2bf(W[k * 128 + c]);
  }
}

// ======= fused: EDGE CSR build (atomic wall) + MFMA GEMM (hides under it) ===
// Wall model (R6-R21): scattered atomics = one 32B coherence-point sector
// each @ ~19 G/s, op-count-proportional. R21 showed ZERO overlap with the
// GEMM because each thread's lst_e store WAITS on its atomic's return before
// entering the GEMM. Fix: one edge per thread (grid*256 == EA), issue both
// atomics up front, hold (s,t,p) in VGPRs, run the GEMM, store lst_e in the
// epilogue — atomic latency drains under the MFMA work.
__global__ __launch_bounds__(256) void k_fused(
    const int* __restrict__ ei, int* __restrict__ cnt_src,
    int* __restrict__ cnt_e, int* __restrict__ lst_e,
    const float* __restrict__ xa, const ushort_t* __restrict__ Wt,
    const float* __restrict__ b, ushort_t* __restrict__ y) {
  __shared__ ushort_t Asl[64 * CSTR];    // 5.0 KB
  __shared__ ushort_t Bsl[128 * CSTR];   // 10.0 KB
  const int tid = threadIdx.x;
  const int brow = blockIdx.x * 64;

  // ---- phase 1: issue edge-build atomics (exactly one edge per thread) ----
  const int eidx = blockIdx.x * 256 + tid;
  const int s_e = ei[eidx];
  const int t_e = ei[EA + eidx];
  atomicAdd(&cnt_src[s_e], 1);                 // fire-and-forget
  const int p_e = atomicAdd(&cnt_e[t_e], 1);   // consumed in epilogue only

  // ---- phase 2: GEMM y = bf16(x@W + b), K-chunked (4 x K=32) ----
  const int w = tid >> 6;
  const int l = tid & 63;
  const int lr = l & 15;
  const int g = l >> 4;
  const int r0 = w * 16;
  const int arow = r0 + lr;
  f32x4 acc[8] = {};
#pragma unroll
  for (int s = 0; s < 4; ++s) {
    if (s > 0) __syncthreads();  // all reads of chunk s-1 done
    {  // stage A chunk: 64 rows x 32 k
      const float4* gA = reinterpret_cast<const float4*>(xa + (size_t)brow * 128);
#pragma unroll
      for (int i = 0; i < 2; ++i) {
        int f = tid + i * 256;
        int row = f >> 3;
        int kq = f & 7;
        float4 v = gA[row * 32 + s * 8 + kq];
        ushort4 u;
        u.x = f2bf(v.x); u.y = f2bf(v.y); u.z = f2bf(v.z); u.w = f2bf(v.w);
        int off = ((kq & 3) << 3) | ((kq >> 2) << 2);  // g'*8 + 4h
        *reinterpret_cast<ushort4*>(&Asl[row * CSTR + off]) = u;
      }
      // stage B chunk: 128 cols x 32 k
      const uint4* gW = reinterpret_cast<const uint4*>(Wt);
#pragma unroll
      for (int i = 0; i < 2; ++i) {
        int f = tid + i * 256;
        int c = f >> 2;
        int k8 = f & 3;
        uint4 v = gW[c * 16 + s * 4 + k8];
        int base0 = ((k8 & 1) << 4) | ((k8 >> 1) << 2);
        uint2 lo, hi;
        lo.x = v.x; lo.y = v.y;
        hi.x = v.z; hi.y = v.w;
        *reinterpret_cast<uint2*>(&Bsl[c * CSTR + base0]) = lo;
        *reinterpret_cast<uint2*>(&Bsl[c * CSTR + base0 + 8]) = hi;
      }
    }
    __syncthreads();
    bf16x8 a = *reinterpret_cast<const bf16x8*>(&Asl[arow * CSTR + g * 8]);
#pragma unroll
    for (int t = 0; t < 8; ++t) {
      bf16x8 bf = *reinterpret_cast<const bf16x8*>(&Bsl[(t * 16 + lr) * CSTR + g * 8]);
      acc[t] = __builtin_amdgcn_mfma_f32_16x16x32_bf16(a, bf, acc[t], 0, 0, 0);
    }
  }
#pragma unroll
  for (int t = 0; t < 8; ++t) {
    const int col = t * 16 + lr;
    const float bb = b[col];
#pragma unroll
    for (int r = 0; r < 4; ++r) {
      const int row = brow + r0 + g * 4 + r;
      y[(size_t)row * 128 + col] = f2bf(acc[t][r] + bb);
    }
  }

  // ---- epilogue: deferred CSR placement (atomic long since returned) ----
  if (p_e < CAPE) lst_e[t_e * CAPE + p_e] = s_e;
}

// ==== frag-build prologue + x_new gather ====================================
__global__ __launch_bounds__(256) void k_gather_x(
    const int* __restrict__ a2f, const int* __restrict__ fi,
    int* __restrict__ cnt_a, int* __restrict__ cnt_f,
    int* __restrict__ lst_a, int* __restrict__ lst_f,
    const int* __restrict__ cnt_e, const int* __restrict__ lst_e,
    const ushort_t* __restrict__ y, const int* __restrict__ cnt_src,
    float* __restrict__ xnew, ushort_t* __restrict__ x16) {
  {  // frag-build: NA + EF = 260K items over 3.2M threads (single pass)
    int idx = blockIdx.x * 256 + threadIdx.x;
    if (idx < NA) {
      int f = a2f[idx];
      int p = atomicAdd(&cnt_a[f], 1);
      if (p < CAPA) lst_a[f * CAPA + p] = idx;
    } else if (idx < NA + EF) {
      int e = idx - NA;
      int t = fi[EF + e];
      int p = atomicAdd(&cnt_f[t], 1);
      if (p < CAPF) lst_f[t * CAPF + p] = fi[e];
    }
  }
  const int row = blockIdx.x * 16 + (threadIdx.x >> 4);
  const int lane = threadIdx.x & 15;
  const int c0 = lane * 8;  // bf16 units
  const float dt = rsqrtf(1.0f + (float)cnt_src[row]);
  float a0 = 0, a1 = 0, a2 = 0, a3 = 0, a4 = 0, a5 = 0, a6 = 0, a7 = 0;
  {
    uint4 v = *reinterpret_cast<const uint4*>(y + (size_t)row * 128 + c0);
    acc2s(a0, a1, v.x, dt); acc2s(a2, a3, v.y, dt);
    acc2s(a4, a5, v.z, dt); acc2s(a6, a7, v.w, dt);
  }
  const int base = row * CAPE;
  int deg = cnt_e[row];
  deg = (deg < CAPE) ? deg : CAPE;
  int j = 0;
  for (; j + 4 <= deg; j += 4) {
    const int s0 = lst_e[base + j + 0];
    const int s1 = lst_e[base + j + 1];
    const int s2 = lst_e[base + j + 2];
    const int s3 = lst_e[base + j + 3];
    const float d0 = rsqrtf(1.0f + (float)cnt_src[s0]);
    const float d1 = rsqrtf(1.0f + (float)cnt_src[s1]);
    const float d2 = rsqrtf(1.0f + (float)cnt_src[s2]);
    const float d3 = rsqrtf(1.0f + (float)cnt_src[s3]);
    const uint4 w0 = *reinterpret_cast<const uint4*>(y + (size_t)s0 * 128 + c0);
    const uint4 w1 = *reinterpret_cast<const uint4*>(y + (size_t)s1 * 128 + c0);
    const uint4 w2 = *reinterpret_cast<const uint4*>(y + (size_t)s2 * 128 + c0);
    const uint4 w3 = *reinterpret_cast<const uint4*>(y + (size_t)s3 * 128 + c0);
    acc2s(a0, a1, w0.x, d0); acc2s(a2, a3, w0.y, d0); acc2s(a4, a5, w0.z, d0); acc2s(a6, a7, w0.w, d0);
    acc2s(a0, a1, w1.x, d1); acc2s(a2, a3, w1.y, d1); acc2s(a4, a5, w1.z, d1); acc2s(a6, a7, w1.w, d1);
    acc2s(a0, a1, w2.x, d2); acc2s(a2, a3, w2.y, d2); acc2s(a4, a5, w2.z, d2); acc2s(a6, a7, w2.w, d2);
    acc2s(a0, a1, w3.x, d3); acc2s(a2, a3, w3.y, d3); acc2s(a4, a5, w3.z, d3); acc2s(a6, a7, w3.w, d3);
  }
  for (; j < deg; ++j) {
    const int s = lst_e[base + j];
    const float dn = rsqrtf(1.0f + (float)cnt_src[s]);
    const uint4 w = *reinterpret_cast<const uint4*>(y + (size_t)s * 128 + c0);
    acc2s(a0, a1, w.x, dn); acc2s(a2, a3, w.y, dn);
    acc2s(a4, a5, w.z, dn); acc2s(a6, a7, w.w, dn);
  }
  a0 *= dt; a1 *= dt; a2 *= dt; a3 *= dt;
  a4 *= dt; a5 *= dt; a6 *= dt; a7 *= dt;
  f32x4 q0 = {a0, a1, a2, a3};
  f32x4 q1 = {a4, a5, a6, a7};
  float* o = xnew + (size_t)row * 128 + c0;
  __builtin_nontemporal_store(q0, reinterpret_cast<f32x4*>(o));
  __builtin_nontemporal_store(q1, reinterpret_cast<f32x4*>(o + 4));
  uint4 hp;
  hp.x = (unsigned)f2bf(a0) | ((unsigned)f2bf(a1) << 16);
  hp.y = (unsigned)f2bf(a2) | ((unsigned)f2bf(a3) << 16);
  hp.z = (unsigned)f2bf(a4) | ((unsigned)f2bf(a5) << 16);
  hp.w = (unsigned)f2bf(a6) | ((unsigned)f2bf(a7) << 16);
  *reinterpret_cast<uint4*>(x16 + (size_t)row * 128 + c0) = hp;
}

// ======== ff[f] = sum_{atoms i in f} xnew[i]  (bf16 sidecar reads) ==========
__global__ __launch_bounds__(256) void k_gather_ff(
    const int* __restrict__ cnt_a, const int* __restrict__ lst_a,
    const ushort_t* __restrict__ x16, float* __restrict__ ff) {
  const int f = blockIdx.x * 16 + (threadIdx.x >> 4);
  const int lane = threadIdx.x & 15;
  const int c0 = lane * 8;  // bf16 units
  float a0 = 0, a1 = 0, a2 = 0, a3 = 0, a4 = 0, a5 = 0, a6 = 0, a7 = 0;
  const int base = f * CAPA;
  int deg = cnt_a[f];
  deg = (deg < CAPA) ? deg : CAPA;
  int j = 0;
  for (; j + 4 <= deg; j += 4) {
    const int s0 = lst_a[base + j + 0];
    const int s1 = lst_a[base + j + 1];
    const int s2 = lst_a[base + j + 2];
    const int s3 = lst_a[base + j + 3];
    const uint4 w0 = *reinterpret_cast<const uint4*>(x16 + (size_t)s0 * 128 + c0);
    const uint4 w1 = *reinterpret_cast<const uint4*>(x16 + (size_t)s1 * 128 + c0);
    const uint4 w2 = *reinterpret_cast<const uint4*>(x16 + (size_t)s2 * 128 + c0);
    const uint4 w3 = *reinterpret_cast<const uint4*>(x16 + (size_t)s3 * 128 + c0);
    acc2(a0, a1, w0.x); acc2(a2, a3, w0.y); acc2(a4, a5, w0.z); acc2(a6, a7, w0.w);
    acc2(a0, a1, w1.x); acc2(a2, a3, w1.y); acc2(a4, a5, w1.z); acc2(a6, a7, w1.w);
    acc2(a0, a1, w2.x); acc2(a2, a3, w2.y); acc2(a4, a5, w2.z); acc2(a6, a7, w2.w);
    acc2(a0, a1, w3.x); acc2(a2, a3, w3.y); acc2(a4, a5, w3.z); acc2(a6, a7, w3.w);
  }
  for (; j < deg; ++j) {
    const int s = lst_a[base + j];
    const uint4 w = *reinterpret_cast<const uint4*>(x16 + (size_t)s * 128 + c0);
    acc2(a0, a1, w.x); acc2(a2, a3, w.y); acc2(a4, a5, w.z); acc2(a6, a7, w.w);
  }
  f32x4 q0 = {a0, a1, a2, a3};
  f32x4 q1 = {a4, a5, a6, a7};
  float* o = ff + (size_t)f * 128 + c0;
  *reinterpret_cast<f32x4*>(o) = q0;
  *reinterpret_cast<f32x4*>(o + 4) = q1;
}

// ======== fused: fsum gather (frag edges) + 2-layer MLP =====================
__global__ __launch_bounds__(256) void k_mlp(
    const int* __restrict__ cnt_f, const int* __restrict__ lst_f,
    const float* __restrict__ ff,
    const float* __restrict__ W1, const float* __restrict__ b1,
    const float* __restrict__ W2, const float* __restrict__ b2,
    float* __restrict__ out) {
  __shared__ float As[32][128];
  __shared__ float hs[32][256];
  const int row0 = blockIdx.x * 32;
  {  // gather: 8 groups x 32 lanes; each group handles 4 rows
    const int g = threadIdx.x >> 5;
    const int c = (threadIdx.x & 31) << 2;
#pragma unroll
    for (int rr = 0; rr < 4; ++rr) {
      const int f = row0 + g * 4 + rr;
      const int base = f * CAPF;
      int deg = cnt_f[f];
      deg = (deg < CAPF) ? deg : CAPF;
      float4 acc = {0.f, 0.f, 0.f, 0.f};
      for (int j = 0; j < deg; ++j) {
        const int s = lst_f[base + j];
        const float4 v = *reinterpret_cast<const float4*>(ff + (size_t)s * 128 + c);
        acc.x += v.x; acc.y += v.y; acc.z += v.z; acc.w += v.w;
      }
      *reinterpret_cast<float4*>(&As[g * 4 + rr][c]) = acc;
    }
  }
  __syncthreads();
  {  // GEMM1
    const int tc = threadIdx.x & 63;
    const int tr = threadIdx.x >> 6;
    const int c0 = tc * 4;
    float acc[8][4] = {};
    for (int k0 = 0; k0 < 128; k0 += 4) {
      float4 w0 = *reinterpret_cast<const float4*>(&W1[(k0 + 0) * 256 + c0]);
      float4 w1 = *reinterpret_cast<const float4*>(&W1[(k0 + 1) * 256 + c0]);
      float4 w2 = *reinterpret_cast<const float4*>(&W1[(k0 + 2) * 256 + c0]);
      float4 w3 = *reinterpret_cast<const float4*>(&W1[(k0 + 3) * 256 + c0]);
#pragma unroll
      for (int r = 0; r < 8; ++r) {
        float4 a = *reinterpret_cast<const float4*>(&As[tr * 8 + r][k0]);
        acc[r][0] += a.x * w0.x + a.y * w1.x + a.z * w2.x + a.w * w3.x;
        acc[r][1] += a.x * w0.y + a.y * w1.y + a.z * w2.y + a.w * w3.y;
        acc[r][2] += a.x * w0.z + a.y * w1.z + a.z * w2.z + a.w * w3.z;
        acc[r][3] += a.x * w0.w + a.y * w1.w + a.z * w2.w + a.w * w3.w;
      }
    }
    const float4 bc = *reinterpret_cast<const float4*>(&b1[c0]);
#pragma unroll
    for (int r = 0; r < 8; ++r) {
      float4 h;
      h.x = fmaxf(acc[r][0] + bc.x, 0.f);
      h.y = fmaxf(acc[r][1] + bc.y, 0.f);
      h.z = fmaxf(acc[r][2] + bc.z, 0.f);
      h.w = fmaxf(acc[r][3] + bc.w, 0.f);
      *reinterpret_cast<float4*>(&hs[tr * 8 + r][c0]) = h;
    }
  }
  __syncthreads();
  {  // GEMM2
    const int tc = threadIdx.x & 31;
    const int tr = threadIdx.x >> 5;
    const int c0 = tc * 4;
    float acc[4][4] = {};
    for (int k0 = 0; k0 < 256; k0 += 4) {
      float4 w0 = *reinterpret_cast<const float4*>(&W2[(k0 + 0) * 128 + c0]);
      float4 w1 = *reinterpret_cast<const float4*>(&W2[(k0 + 1) * 128 + c0]);
      float4 w2 = *reinterpret_cast<const float4*>(&W2[(k0 + 2) * 128 + c0]);
      float4 w3 = *reinterpret_cast<const float4*>(&W2[(k0 + 3) * 128 + c0]);
#pragma unroll
      for (int r = 0; r < 4; ++r) {
        float4 a = *reinterpret_cast<const float4*>(&hs[tr * 4 + r][k0]);
        acc[r][0] += a.x * w0.x + a.y * w1.x + a.z * w2.x + a.w * w3.x;
        acc[r][1] += a.x * w0.y + a.y * w1.y + a.z * w2.y + a.w * w3.y;
        acc[r][2] += a.x * w0.z + a.y * w1.z + a.z * w2.z + a.w * w3.z;
        acc[r][3] += a.x * w0.w + a.y * w1.w + a.z * w2.w + a.w * w3.w;
      }
    }
    const float4 bc = *reinterpret_cast<const float4*>(&b2[c0]);
#pragma unroll
    for (int r = 0; r < 4; ++r) {
      float4 o;
      o.x = acc[r][0] + bc.x;
      o.y = acc[r][1] + bc.y;
      o.z = acc[r][2] + bc.z;
      o.w = acc[r][3] + bc.w;
      *reinterpret_cast<float4*>(&out[(size_t)(row0 + tr * 4 + r) * 128 + c0]) = o;
    }
  }
}

extern "C" void kernel_launch(void* const* d_in, const int* in_sizes, int n_in,
                              void* d_out, int out_size, void* d_ws, size_t ws_size,
                              hipStream_t stream) {
  // Bond-graph GAT inputs are dead code w.r.t. the returned outputs.
  const float* x_atoms    = (const float*)d_in[0];
  const int*   edge_index = (const int*)d_in[1];
  const int*   frag_index = (const int*)d_in[3];
  const int*   a2f        = (const int*)d_in[5];
  const float* W_atom     = (const float*)d_in[9];
  const float* b_atom     = (const float*)d_in[10];
  const float* W_f1       = (const float*)d_in[16];
  const float* b_f1       = (const float*)d_in[17];
  const float* W_f2       = (const float*)d_in[18];
  const float* b_f2       = (const float*)d_in[19];

  char* ws = (char*)d_ws;
  size_t off = 0;
  auto alloc = [&](size_t bytes) {
    void* p = ws + off;
    off += (bytes + 255) & ~(size_t)255;
    return p;
  };
  // --- counters: ONE contiguous block, zeroed by k_init (1.76 MB) ---
  int* cnts    = (int*)alloc((size_t)NCNT * 4);
  int* cnt_src = cnts;
  int* cnt_e   = cnts + NA;
  int* cnt_a   = cnts + 2 * NA;
  int* cnt_f   = cnts + 2 * NA + NF;
  // --- rebuilt-each-call ---
  int* lst_e   = (int*)alloc((size_t)NA * CAPE * 4);   // 25.6 MB
  int* lst_a   = (int*)alloc((size_t)NF * CAPA * 4);   // 5.1 MB
  int* lst_f   = (int*)alloc((size_t)NF * CAPF * 4);   // 2.6 MB
  ushort_t* Wt = (ushort_t*)alloc((size_t)128 * 128 * 2);
  ushort_t* y  = (ushort_t*)alloc((size_t)NA * 128 * 2);   // 51.2 MB
  ushort_t* x16 = (ushort_t*)alloc((size_t)NA * 128 * 2);  // 51.2 MB sidecar
  float* ff    = (float*)alloc((size_t)NF * 128 * 4);      // 10.2 MB

  float* xnew = (float*)d_out;                     // [NA,128]
  float* fout = (float*)d_out + (size_t)NA * 128;  // [NF,128]

  k_init<<<(NCNT + 255) / 256, 256, 0, stream>>>(W_atom, Wt, cnts);
  k_fused<<<GRIDY, 256, 0, stream>>>(edge_index, cnt_src, cnt_e, lst_e,
                                     x_atoms, Wt, b_atom, y);
  k_gather_x<<<GRIDX, 256, 0, stream>>>(a2f, frag_index, cnt_a, cnt_f,
                                        lst_a, lst_f, cnt_e, lst_e, y,
                                        cnt_src, xnew, x16);
  k_gather_ff<<<NF / 16, 256, 0, stream>>>(cnt_a, lst_a, x16, ff);
  k_mlp<<<NF / 32, 256, 0, stream>>>(cnt_f, lst_f, ff, W_f1, b_f1,
                                     W_f2, b_f2, fout);
}

// Round 23
// 245.230 us; speedup vs baseline: 1.1269x; 1.0125x over previous
//
#include <hip/hip_runtime.h>
#include <hip/hip_bf16.h>
#include <cstddef>

#define NA 200000   // atoms
#define EA 800000   // atom-graph edges
#define NF 20000    // fragments
#define EF 60000    // fragment-graph edges
// D = 128, hidden = 256
#define CAPE 32               // max in-degree (atom edges; Poisson mean 4)
#define CAPA 64               // max atoms/frag (Poisson mean 10)
#define CAPF 32               // max frag-edge in-degree (Poisson mean 3)
#define GRIDY (NA / 64)       // fused-kernel grid (3125 blocks; x256 thr == EA)
#define CSTR 40               // chunk LDS row stride in ushorts (80B)
#define NCNT (2 * NA + 2 * NF) // total counter words (zeroed each call)
#define GRIDX (NA / 16)       // gather_x grid (12500 blocks)

typedef unsigned short ushort_t;
typedef __attribute__((ext_vector_type(8))) short bf16x8;
typedef __attribute__((ext_vector_type(4))) float f32x4;

__device__ __forceinline__ unsigned short f2bf(float f) {
  unsigned u = __builtin_bit_cast(unsigned, f);
  u += 0x7FFFu + ((u >> 16) & 1u);  // round-to-nearest-even
  return (unsigned short)(u >> 16);
}
// fma 2 bf16 packed in a uint (lo, hi) scaled by s
__device__ __forceinline__ void acc2s(float& a, float& b, unsigned v, float s) {
  a = fmaf(__builtin_bit_cast(float, v << 16), s, a);
  b = fmaf(__builtin_bit_cast(float, v & 0xFFFF0000u), s, b);
}
__device__ __forceinline__ void acc2(float& a, float& b, unsigned v) {
  a += __builtin_bit_cast(float, v << 16);
  b += __builtin_bit_cast(float, v & 0xFFFF0000u);
}

// ======== init: zero counters + Wt[c][k] = bf16(W[k][c]) (one launch) =======
__global__ __launch_bounds__(256) void k_init(const float* __restrict__ W,
                                              ushort_t* __restrict__ Wt,
                                              int* __restrict__ cnts) {
  int idx = blockIdx.x * 256 + threadIdx.x;
  if (idx < NCNT) cnts[idx] = 0;
  if (idx < 128 * 128) {
    int c = idx >> 7, k = idx & 127;
    Wt[idx] = f2bf(W[k * 128 + c]);
  }
}

// ======= fused: EDGE CSR build (atomic wall) + MFMA GEMM (hides under it) ===
// Wall model (R6-R22): scattered atomics = one 32B coherence-point sector
// each @ ~19 G/s, op-count-proportional. vmcnt retires IN ORDER, so any
// staging-load wait issued after the atomics forces atomic completion
// (R22's residual 16us). Fix: hoist ALL staging loads (full A tile + full
// Wt into registers) ABOVE the atomic issue — every ds_write then waits
// only vmcnt(2), leaving the 2 atomics in flight across the whole GEMM;
// p_e is consumed only in the epilogue.
__global__ __launch_bounds__(256) void k_fused(
    const int* __restrict__ ei, int* __restrict__ cnt_src,
    int* __restrict__ cnt_e, int* __restrict__ lst_e,
    const float* __restrict__ xa, const ushort_t* __restrict__ Wt,
    const float* __restrict__ b, ushort_t* __restrict__ y) {
  __shared__ ushort_t Asl[64 * CSTR];    // 5.0 KB
  __shared__ ushort_t Bsl[128 * CSTR];   // 10.0 KB
  const int tid = threadIdx.x;
  const int brow = blockIdx.x * 64;

  // ---- upfront: ALL staging loads (16 vmem ops) ----
  float4 ar[8];  // full 64x128 A tile: ar[i] = gA[tid + i*256]
  uint4 br[8];   // full 128x128 Wt:    br[i] = gW[tid + i*256]
  {
    const float4* gA = reinterpret_cast<const float4*>(xa + (size_t)brow * 128);
    const uint4* gW = reinterpret_cast<const uint4*>(Wt);
#pragma unroll
    for (int i = 0; i < 8; ++i) ar[i] = gA[tid + i * 256];
#pragma unroll
    for (int i = 0; i < 8; ++i) br[i] = gW[tid + i * 256];
  }

  // ---- issue edge-build atomics (exactly one edge per thread) ----
  const int eidx = blockIdx.x * 256 + tid;
  const int s_e = ei[eidx];
  const int t_e = ei[EA + eidx];
  atomicAdd(&cnt_src[s_e], 1);                 // fire-and-forget
  const int p_e = atomicAdd(&cnt_e[t_e], 1);   // consumed in epilogue only

  // ---- GEMM y = bf16(x@W + b), K-chunked (4 x K=32), LDS fed from regs ----
  // Reg->chunk partition: A regs of thread belong to chunk (tid>>3)&3
  // (kq_full = tid&31 constant over i; row = (tid>>5)+8i). B regs belong to
  // chunk (tid>>2)&3 (k8_full = tid&15; c = (tid>>4)+16i).
  const int w = tid >> 6;
  const int l = tid & 63;
  const int lr = l & 15;
  const int g = l >> 4;
  const int r0 = w * 16;
  const int arow = r0 + lr;
  f32x4 acc[8] = {};
#pragma unroll
  for (int s = 0; s < 4; ++s) {
    if (s > 0) __syncthreads();  // all reads of chunk s-1 done
    if (((tid >> 3) & 3) == s) {  // A writers: 64 threads, 8 rows each
      const int kql = tid & 7;
      const int off = ((kql & 3) << 3) | ((kql >> 2) << 2);  // g'*8 + 4h
      const int a0r = tid >> 5;
#pragma unroll
      for (int i = 0; i < 8; ++i) {
        ushort4 u;
        u.x = f2bf(ar[i].x); u.y = f2bf(ar[i].y);
        u.z = f2bf(ar[i].z); u.w = f2bf(ar[i].w);
        *reinterpret_cast<ushort4*>(&Asl[(a0r + i * 8) * CSTR + off]) = u;
      }
    }
    if (((tid >> 2) & 3) == s) {  // B writers: 64 threads, 8 cols each
      const int k8l = tid & 3;
      const int base0 = ((k8l & 1) << 4) | ((k8l >> 1) << 2);
      const int c0b = tid >> 4;
#pragma unroll
      for (int i = 0; i < 8; ++i) {
        const int c = c0b + i * 16;
        uint2 lo, hi;
        lo.x = br[i].x; lo.y = br[i].y;
        hi.x = br[i].z; hi.y = br[i].w;
        *reinterpret_cast<uint2*>(&Bsl[c * CSTR + base0]) = lo;
        *reinterpret_cast<uint2*>(&Bsl[c * CSTR + base0 + 8]) = hi;
      }
    }
    __syncthreads();
    bf16x8 a = *reinterpret_cast<const bf16x8*>(&Asl[arow * CSTR + g * 8]);
#pragma unroll
    for (int t = 0; t < 8; ++t) {
      bf16x8 bf = *reinterpret_cast<const bf16x8*>(&Bsl[(t * 16 + lr) * CSTR + g * 8]);
      acc[t] = __builtin_amdgcn_mfma_f32_16x16x32_bf16(a, bf, acc[t], 0, 0, 0);
    }
  }
#pragma unroll
  for (int t = 0; t < 8; ++t) {
    const int col = t * 16 + lr;
    const float bb = b[col];
#pragma unroll
    for (int r = 0; r < 4; ++r) {
      const int row = brow + r0 + g * 4 + r;
      y[(size_t)row * 128 + col] = f2bf(acc[t][r] + bb);
    }
  }

  // ---- epilogue: deferred CSR placement (atomic drained under the GEMM) ----
  if (p_e < CAPE) lst_e[t_e * CAPE + p_e] = s_e;
}

// ==== frag-build prologue (deferred placement) + x_new gather ===============
__global__ __launch_bounds__(256) void k_gather_x(
    const int* __restrict__ a2f, const int* __restrict__ fi,
    int* __restrict__ cnt_a, int* __restrict__ cnt_f,
    int* __restrict__ lst_a, int* __restrict__ lst_f,
    const int* __restrict__ cnt_e, const int* __restrict__ lst_e,
    const ushort_t* __restrict__ y, const int* __restrict__ cnt_src,
    float* __restrict__ xnew, ushort_t* __restrict__ x16) {
  // issue frag-build atomics; placement deferred to epilogue
  int fa = -1, pa = 0, ia = 0;
  int tf = -1, pf = 0, sf = 0;
  {
    int idx = blockIdx.x * 256 + threadIdx.x;
    if (idx < NA) {
      fa = a2f[idx]; ia = idx;
      pa = atomicAdd(&cnt_a[fa], 1);
    } else if (idx < NA + EF) {
      int e = idx - NA;
      tf = fi[EF + e]; sf = fi[e];
      pf = atomicAdd(&cnt_f[tf], 1);
    }
  }
  const int row = blockIdx.x * 16 + (threadIdx.x >> 4);
  const int lane = threadIdx.x & 15;
  const int c0 = lane * 8;  // bf16 units
  const float dt = rsqrtf(1.0f + (float)cnt_src[row]);
  float a0 = 0, a1 = 0, a2 = 0, a3 = 0, a4 = 0, a5 = 0, a6 = 0, a7 = 0;
  {
    uint4 v = *reinterpret_cast<const uint4*>(y + (size_t)row * 128 + c0);
    acc2s(a0, a1, v.x, dt); acc2s(a2, a3, v.y, dt);
    acc2s(a4, a5, v.z, dt); acc2s(a6, a7, v.w, dt);
  }
  const int base = row * CAPE;
  int deg = cnt_e[row];
  deg = (deg < CAPE) ? deg : CAPE;
  int j = 0;
  for (; j + 4 <= deg; j += 4) {
    const int s0 = lst_e[base + j + 0];
    const int s1 = lst_e[base + j + 1];
    const int s2 = lst_e[base + j + 2];
    const int s3 = lst_e[base + j + 3];
    const float d0 = rsqrtf(1.0f + (float)cnt_src[s0]);
    const float d1 = rsqrtf(1.0f + (float)cnt_src[s1]);
    const float d2 = rsqrtf(1.0f + (float)cnt_src[s2]);
    const float d3 = rsqrtf(1.0f + (float)cnt_src[s3]);
    const uint4 w0 = *reinterpret_cast<const uint4*>(y + (size_t)s0 * 128 + c0);
    const uint4 w1 = *reinterpret_cast<const uint4*>(y + (size_t)s1 * 128 + c0);
    const uint4 w2 = *reinterpret_cast<const uint4*>(y + (size_t)s2 * 128 + c0);
    const uint4 w3 = *reinterpret_cast<const uint4*>(y + (size_t)s3 * 128 + c0);
    acc2s(a0, a1, w0.x, d0); acc2s(a2, a3, w0.y, d0); acc2s(a4, a5, w0.z, d0); acc2s(a6, a7, w0.w, d0);
    acc2s(a0, a1, w1.x, d1); acc2s(a2, a3, w1.y, d1); acc2s(a4, a5, w1.z, d1); acc2s(a6, a7, w1.w, d1);
    acc2s(a0, a1, w2.x, d2); acc2s(a2, a3, w2.y, d2); acc2s(a4, a5, w2.z, d2); acc2s(a6, a7, w2.w, d2);
    acc2s(a0, a1, w3.x, d3); acc2s(a2, a3, w3.y, d3); acc2s(a4, a5, w3.z, d3); acc2s(a6, a7, w3.w, d3);
  }
  for (; j < deg; ++j) {
    const int s = lst_e[base + j];
    const float dn = rsqrtf(1.0f + (float)cnt_src[s]);
    const uint4 w = *reinterpret_cast<const uint4*>(y + (size_t)s * 128 + c0);
    acc2s(a0, a1, w.x, dn); acc2s(a2, a3, w.y, dn);
    acc2s(a4, a5, w.z, dn); acc2s(a6, a7, w.w, dn);
  }
  a0 *= dt; a1 *= dt; a2 *= dt; a3 *= dt;
  a4 *= dt; a5 *= dt; a6 *= dt; a7 *= dt;
  f32x4 q0 = {a0, a1, a2, a3};
  f32x4 q1 = {a4, a5, a6, a7};
  float* o = xnew + (size_t)row * 128 + c0;
  __builtin_nontemporal_store(q0, reinterpret_cast<f32x4*>(o));
  __builtin_nontemporal_store(q1, reinterpret_cast<f32x4*>(o + 4));
  uint4 hp;
  hp.x = (unsigned)f2bf(a0) | ((unsigned)f2bf(a1) << 16);
  hp.y = (unsigned)f2bf(a2) | ((unsigned)f2bf(a3) << 16);
  hp.z = (unsigned)f2bf(a4) | ((unsigned)f2bf(a5) << 16);
  hp.w = (unsigned)f2bf(a6) | ((unsigned)f2bf(a7) << 16);
  *reinterpret_cast<uint4*>(x16 + (size_t)row * 128 + c0) = hp;
  // deferred frag-CSR placement
  if (fa >= 0 && pa < CAPA) lst_a[fa * CAPA + pa] = ia;
  if (tf >= 0 && pf < CAPF) lst_f[tf * CAPF + pf] = sf;
}

// ======== ff[f] = sum_{atoms i in f} xnew[i]  (bf16 sidecar reads) ==========
__global__ __launch_bounds__(256) void k_gather_ff(
    const int* __restrict__ cnt_a, const int* __restrict__ lst_a,
    const ushort_t* __restrict__ x16, float* __restrict__ ff) {
  const int f = blockIdx.x * 16 + (threadIdx.x >> 4);
  const int lane = threadIdx.x & 15;
  const int c0 = lane * 8;  // bf16 units
  float a0 = 0, a1 = 0, a2 = 0, a3 = 0, a4 = 0, a5 = 0, a6 = 0, a7 = 0;
  const int base = f * CAPA;
  int deg = cnt_a[f];
  deg = (deg < CAPA) ? deg : CAPA;
  int j = 0;
  for (; j + 4 <= deg; j += 4) {
    const int s0 = lst_a[base + j + 0];
    const int s1 = lst_a[base + j + 1];
    const int s2 = lst_a[base + j + 2];
    const int s3 = lst_a[base + j + 3];
    const uint4 w0 = *reinterpret_cast<const uint4*>(x16 + (size_t)s0 * 128 + c0);
    const uint4 w1 = *reinterpret_cast<const uint4*>(x16 + (size_t)s1 * 128 + c0);
    const uint4 w2 = *reinterpret_cast<const uint4*>(x16 + (size_t)s2 * 128 + c0);
    const uint4 w3 = *reinterpret_cast<const uint4*>(x16 + (size_t)s3 * 128 + c0);
    acc2(a0, a1, w0.x); acc2(a2, a3, w0.y); acc2(a4, a5, w0.z); acc2(a6, a7, w0.w);
    acc2(a0, a1, w1.x); acc2(a2, a3, w1.y); acc2(a4, a5, w1.z); acc2(a6, a7, w1.w);
    acc2(a0, a1, w2.x); acc2(a2, a3, w2.y); acc2(a4, a5, w2.z); acc2(a6, a7, w2.w);
    acc2(a0, a1, w3.x); acc2(a2, a3, w3.y); acc2(a4, a5, w3.z); acc2(a6, a7, w3.w);
  }
  for (; j < deg; ++j) {
    const int s = lst_a[base + j];
    const uint4 w = *reinterpret_cast<const uint4*>(x16 + (size_t)s * 128 + c0);
    acc2(a0, a1, w.x); acc2(a2, a3, w.y); acc2(a4, a5, w.z); acc2(a6, a7, w.w);
  }
  f32x4 q0 = {a0, a1, a2, a3};
  f32x4 q1 = {a4, a5, a6, a7};
  float* o = ff + (size_t)f * 128 + c0;
  *reinterpret_cast<f32x4*>(o) = q0;
  *reinterpret_cast<f32x4*>(o + 4) = q1;
}

// ======== fused: fsum gather (frag edges) + 2-layer MLP =====================
__global__ __launch_bounds__(256) void k_mlp(
    const int* __restrict__ cnt_f, const int* __restrict__ lst_f,
    const float* __restrict__ ff,
    const float* __restrict__ W1, const float* __restrict__ b1,
    const float* __restrict__ W2, const float* __restrict__ b2,
    float* __restrict__ out) {
  __shared__ float As[32][128];
  __shared__ float hs[32][256];
  const int row0 = blockIdx.x * 32;
  {  // gather: 8 groups x 32 lanes; each group handles 4 rows
    const int g = threadIdx.x >> 5;
    const int c = (threadIdx.x & 31) << 2;
#pragma unroll
    for (int rr = 0; rr < 4; ++rr) {
      const int f = row0 + g * 4 + rr;
      const int base = f * CAPF;
      int deg = cnt_f[f];
      deg = (deg < CAPF) ? deg : CAPF;
      float4 acc = {0.f, 0.f, 0.f, 0.f};
      for (int j = 0; j < deg; ++j) {
        const int s = lst_f[base + j];
        const float4 v = *reinterpret_cast<const float4*>(ff + (size_t)s * 128 + c);
        acc.x += v.x; acc.y += v.y; acc.z += v.z; acc.w += v.w;
      }
      *reinterpret_cast<float4*>(&As[g * 4 + rr][c]) = acc;
    }
  }
  __syncthreads();
  {  // GEMM1
    const int tc = threadIdx.x & 63;
    const int tr = threadIdx.x >> 6;
    const int c0 = tc * 4;
    float acc[8][4] = {};
    for (int k0 = 0; k0 < 128; k0 += 4) {
      float4 w0 = *reinterpret_cast<const float4*>(&W1[(k0 + 0) * 256 + c0]);
      float4 w1 = *reinterpret_cast<const float4*>(&W1[(k0 + 1) * 256 + c0]);
      float4 w2 = *reinterpret_cast<const float4*>(&W1[(k0 + 2) * 256 + c0]);
      float4 w3 = *reinterpret_cast<const float4*>(&W1[(k0 + 3) * 256 + c0]);
#pragma unroll
      for (int r = 0; r < 8; ++r) {
        float4 a = *reinterpret_cast<const float4*>(&As[tr * 8 + r][k0]);
        acc[r][0] += a.x * w0.x + a.y * w1.x + a.z * w2.x + a.w * w3.x;
        acc[r][1] += a.x * w0.y + a.y * w1.y + a.z * w2.y + a.w * w3.y;
        acc[r][2] += a.x * w0.z + a.y * w1.z + a.z * w2.z + a.w * w3.z;
        acc[r][3] += a.x * w0.w + a.y * w1.w + a.z * w2.w + a.w * w3.w;
      }
    }
    const float4 bc = *reinterpret_cast<const float4*>(&b1[c0]);
#pragma unroll
    for (int r = 0; r < 8; ++r) {
      float4 h;
      h.x = fmaxf(acc[r][0] + bc.x, 0.f);
      h.y = fmaxf(acc[r][1] + bc.y, 0.f);
      h.z = fmaxf(acc[r][2] + bc.z, 0.f);
      h.w = fmaxf(acc[r][3] + bc.w, 0.f);
      *reinterpret_cast<float4*>(&hs[tr * 8 + r][c0]) = h;
    }
  }
  __syncthreads();
  {  // GEMM2
    const int tc = threadIdx.x & 31;
    const int tr = threadIdx.x >> 5;
    const int c0 = tc * 4;
    float acc[4][4] = {};
    for (int k0 = 0; k0 < 256; k0 += 4) {
      float4 w0 = *reinterpret_cast<const float4*>(&W2[(k0 + 0) * 128 + c0]);
      float4 w1 = *reinterpret_cast<const float4*>(&W2[(k0 + 1) * 128 + c0]);
      float4 w2 = *reinterpret_cast<const float4*>(&W2[(k0 + 2) * 128 + c0]);
      float4 w3 = *reinterpret_cast<const float4*>(&W2[(k0 + 3) * 128 + c0]);
#pragma unroll
      for (int r = 0; r < 4; ++r) {
        float4 a = *reinterpret_cast<const float4*>(&hs[tr * 4 + r][k0]);
        acc[r][0] += a.x * w0.x + a.y * w1.x + a.z * w2.x + a.w * w3.x;
        acc[r][1] += a.x * w0.y + a.y * w1.y + a.z * w2.y + a.w * w3.y;
        acc[r][2] += a.x * w0.z + a.y * w1.z + a.z * w2.z + a.w * w3.z;
        acc[r][3] += a.x * w0.w + a.y * w1.w + a.z * w2.w + a.w * w3.w;
      }
    }
    const float4 bc = *reinterpret_cast<const float4*>(&b2[c0]);
#pragma unroll
    for (int r = 0; r < 4; ++r) {
      float4 o;
      o.x = acc[r][0] + bc.x;
      o.y = acc[r][1] + bc.y;
      o.z = acc[r][2] + bc.z;
      o.w = acc[r][3] + bc.w;
      *reinterpret_cast<float4*>(&out[(size_t)(row0 + tr * 4 + r) * 128 + c0]) = o;
    }
  }
}

extern "C" void kernel_launch(void* const* d_in, const int* in_sizes, int n_in,
                              void* d_out, int out_size, void* d_ws, size_t ws_size,
                              hipStream_t stream) {
  // Bond-graph GAT inputs are dead code w.r.t. the returned outputs.
  const float* x_atoms    = (const float*)d_in[0];
  const int*   edge_index = (const int*)d_in[1];
  const int*   frag_index = (const int*)d_in[3];
  const int*   a2f        = (const int*)d_in[5];
  const float* W_atom     = (const float*)d_in[9];
  const float* b_atom     = (const float*)d_in[10];
  const float* W_f1       = (const float*)d_in[16];
  const float* b_f1       = (const float*)d_in[17];
  const float* W_f2       = (const float*)d_in[18];
  const float* b_f2       = (const float*)d_in[19];

  char* ws = (char*)d_ws;
  size_t off = 0;
  auto alloc = [&](size_t bytes) {
    void* p = ws + off;
    off += (bytes + 255) & ~(size_t)255;
    return p;
  };
  // --- counters: ONE contiguous block, zeroed by k_init (1.76 MB) ---
  int* cnts    = (int*)alloc((size_t)NCNT * 4);
  int* cnt_src = cnts;
  int* cnt_e   = cnts + NA;
  int* cnt_a   = cnts + 2 * NA;
  int* cnt_f   = cnts + 2 * NA + NF;
  // --- rebuilt-each-call ---
  int* lst_e   = (int*)alloc((size_t)NA * CAPE * 4);   // 25.6 MB
  int* lst_a   = (int*)alloc((size_t)NF * CAPA * 4);   // 5.1 MB
  int* lst_f   = (int*)alloc((size_t)NF * CAPF * 4);   // 2.6 MB
  ushort_t* Wt = (ushort_t*)alloc((size_t)128 * 128 * 2);
  ushort_t* y  = (ushort_t*)alloc((size_t)NA * 128 * 2);   // 51.2 MB
  ushort_t* x16 = (ushort_t*)alloc((size_t)NA * 128 * 2);  // 51.2 MB sidecar
  float* ff    = (float*)alloc((size_t)NF * 128 * 4);      // 10.2 MB

  float* xnew = (float*)d_out;                     // [NA,128]
  float* fout = (float*)d_out + (size_t)NA * 128;  // [NF,128]

  k_init<<<(NCNT + 255) / 256, 256, 0, stream>>>(W_atom, Wt, cnts);
  k_fused<<<GRIDY, 256, 0, stream>>>(edge_index, cnt_src, cnt_e, lst_e,
                                     x_atoms, Wt, b_atom, y);
  k_gather_x<<<GRIDX, 256, 0, stream>>>(a2f, frag_index, cnt_a, cnt_f,
                                        lst_a, lst_f, cnt_e, lst_e, y,
                                        cnt_src, xnew, x16);
  k_gather_ff<<<NF / 16, 256, 0, stream>>>(cnt_a, lst_a, x16, ff);
  k_mlp<<<NF / 32, 256, 0, stream>>>(cnt_f, lst_f, ff, W_f1, b_f1,
                                     W_f2, b_f2, fout);
}